// Round 8
// baseline (346.167 us; speedup 1.0000x reference)
//
#include <hip/hip_runtime.h>
#include <math.h>

#define N_NODES 50000
#define E_EDGES 800000
#define ET (E_EDGES + N_NODES)   // edges + self loops
#define IN_F 256
#define HID 128
#define HEADS1 8
#define C1 16
#define OUT_F 64
#define NEG_SLOPE 0.2f
#define NBLK ((N_NODES + 255) / 256)   // 196 scan blocks
#define NRANGE 8
#define RSPAN ((N_NODES + NRANGE - 1) / NRANGE)   // 6250
#define BPG 256                                    // blocks per range-group

typedef __attribute__((ext_vector_type(8))) short short8;
typedef __attribute__((ext_vector_type(4))) float float4v;

__device__ __forceinline__ float lrelu(float v) { return v > 0.f ? v : NEG_SLOPE * v; }

__device__ __forceinline__ unsigned short f2bf(float f) {
  union { float f; unsigned u; } v; v.f = f;
  unsigned r = v.u + 0x7FFF + ((v.u >> 16) & 1);   // RNE
  return (unsigned short)(r >> 16);
}
__device__ __forceinline__ float bf2f(unsigned short u) {
  union { unsigned u; float f; } v; v.u = ((unsigned)u) << 16; return v.f;
}

// ---- W transpose+cast: Wt[n][k] bf16 from W[k][n] fp32 ----
__global__ __launch_bounds__(256) void wt_kernel(const float* __restrict__ W,
                                                 unsigned short* __restrict__ Wt,
                                                 int K, int Nc) {
  int i = blockIdx.x * 256 + threadIdx.x;
  if (i >= K * Nc) return;
  int n = i / K, k = i - n * K;
  Wt[i] = f2bf(W[k * Nc + n]);
}

// ---------------- GEMM1 (MFMA) + fused att1 epilogue ----------------
// h1bf[N,128] = x[N,256] @ W1 ; a_s/a_d[N,8] from fp32 accumulators.
__global__ __launch_bounds__(256) void gemm1_mfma_kernel(const float* __restrict__ x,
                                                         const unsigned short* __restrict__ W1t,
                                                         const float* __restrict__ att_src,
                                                         const float* __restrict__ att_dst,
                                                         unsigned short* __restrict__ h1bf,
                                                         float* __restrict__ a_s,
                                                         float* __restrict__ a_d) {
  const int wave = blockIdx.x * 4 + (threadIdx.x >> 6);
  const int lane = threadIdx.x & 63;
  const int m0 = wave * 16;
  if (m0 >= N_NODES) return;
  const int lm = lane & 15;
  const int quad = lane >> 4;
  const int mrow = m0 + lm;
  const bool valid = mrow < N_NODES;
  const float* arow = x + (size_t)mrow * IN_F;

  float4v acc[8];
#pragma unroll
  for (int nt = 0; nt < 8; ++nt) acc[nt] = (float4v){0.f, 0.f, 0.f, 0.f};

#pragma unroll
  for (int k0 = 0; k0 < IN_F; k0 += 32) {
    short8 a;
    if (valid) {
      float4 f0 = *(const float4*)(arow + k0 + quad * 8);
      float4 f1 = *(const float4*)(arow + k0 + quad * 8 + 4);
      a[0] = f2bf(f0.x); a[1] = f2bf(f0.y); a[2] = f2bf(f0.z); a[3] = f2bf(f0.w);
      a[4] = f2bf(f1.x); a[5] = f2bf(f1.y); a[6] = f2bf(f1.z); a[7] = f2bf(f1.w);
    } else {
      a = (short8){0, 0, 0, 0, 0, 0, 0, 0};
    }
#pragma unroll
    for (int nt = 0; nt < 8; ++nt) {
      short8 b = *(const short8*)&W1t[(size_t)(nt * 16 + lm) * IN_F + k0 + quad * 8];
      acc[nt] = __builtin_amdgcn_mfma_f32_16x16x32_bf16(a, b, acc[nt], 0, 0, 0);
    }
  }

#pragma unroll
  for (int nt = 0; nt < 8; ++nt) {
#pragma unroll
    for (int r = 0; r < 4; ++r) {
      int row = m0 + quad * 4 + r;
      if (row < N_NODES) h1bf[(size_t)row * HID + nt * 16 + lm] = f2bf(acc[nt][r]);
    }
  }

  // ---- fused att1: per-head dot over cols; reduce over lm (16 lanes) ----
  float asv[8], adv[8];
#pragma unroll
  for (int nt = 0; nt < 8; ++nt) { asv[nt] = att_src[nt * 16 + lm]; adv[nt] = att_dst[nt * 16 + lm]; }
#pragma unroll
  for (int r = 0; r < 4; ++r) {
    int row = m0 + quad * 4 + r;
    float s[8], d[8];
#pragma unroll
    for (int nt = 0; nt < 8; ++nt) { s[nt] = acc[nt][r] * asv[nt]; d[nt] = acc[nt][r] * adv[nt]; }
#pragma unroll
    for (int m = 1; m < 16; m <<= 1) {
#pragma unroll
      for (int nt = 0; nt < 8; ++nt) { s[nt] += __shfl_xor(s[nt], m); d[nt] += __shfl_xor(d[nt], m); }
    }
    if (lm == 0 && row < N_NODES) {
#pragma unroll
      for (int nt = 0; nt < 8; ++nt) {
        a_s[(size_t)row * HEADS1 + nt] = s[nt];
        a_d[(size_t)row * HEADS1 + nt] = d[nt];
      }
    }
  }
}

// ---------------- GEMM2 (MFMA) + fused att2 epilogue ----------------
__global__ __launch_bounds__(256) void gemm2_mfma_kernel(const unsigned short* __restrict__ in,
                                                         const unsigned short* __restrict__ W2t,
                                                         const float* __restrict__ att_src,
                                                         const float* __restrict__ att_dst,
                                                         unsigned short* __restrict__ h2bf,
                                                         float* __restrict__ a_s,
                                                         float* __restrict__ a_d) {
  const int wave = blockIdx.x * 4 + (threadIdx.x >> 6);
  const int lane = threadIdx.x & 63;
  const int m0 = wave * 16;
  if (m0 >= N_NODES) return;
  const int lm = lane & 15;
  const int quad = lane >> 4;
  const int mrow = m0 + lm;
  const bool valid = mrow < N_NODES;
  const unsigned short* arow = in + (size_t)mrow * HID;

  float4v acc[4];
#pragma unroll
  for (int nt = 0; nt < 4; ++nt) acc[nt] = (float4v){0.f, 0.f, 0.f, 0.f};

#pragma unroll
  for (int k0 = 0; k0 < HID; k0 += 32) {
    short8 a = valid ? *(const short8*)(arow + k0 + quad * 8)
                     : (short8){0, 0, 0, 0, 0, 0, 0, 0};
#pragma unroll
    for (int nt = 0; nt < 4; ++nt) {
      short8 b = *(const short8*)&W2t[(size_t)(nt * 16 + lm) * HID + k0 + quad * 8];
      acc[nt] = __builtin_amdgcn_mfma_f32_16x16x32_bf16(a, b, acc[nt], 0, 0, 0);
    }
  }

#pragma unroll
  for (int nt = 0; nt < 4; ++nt) {
#pragma unroll
    for (int r = 0; r < 4; ++r) {
      int row = m0 + quad * 4 + r;
      if (row < N_NODES) h2bf[(size_t)row * OUT_F + nt * 16 + lm] = f2bf(acc[nt][r]);
    }
  }

  // ---- fused att2: single head over 64 cols ----
  float as0 = att_src[lm], as1v = att_src[16 + lm], as2v = att_src[32 + lm], as3 = att_src[48 + lm];
  float ad0 = att_dst[lm], ad1v = att_dst[16 + lm], ad2v = att_dst[32 + lm], ad3 = att_dst[48 + lm];
#pragma unroll
  for (int r = 0; r < 4; ++r) {
    int row = m0 + quad * 4 + r;
    float s = acc[0][r] * as0 + acc[1][r] * as1v + acc[2][r] * as2v + acc[3][r] * as3;
    float d = acc[0][r] * ad0 + acc[1][r] * ad1v + acc[2][r] * ad2v + acc[3][r] * ad3;
#pragma unroll
    for (int m = 1; m < 16; m <<= 1) { s += __shfl_xor(s, m); d += __shfl_xor(d, m); }
    if (lm == 0 && row < N_NODES) { a_s[row] = s; a_d[row] = d; }
  }
}

// ---------------- CSR construction (dst-range partitioned for L2 locality) ------
__global__ __launch_bounds__(256) void deg_part_kernel(const int* __restrict__ ei,
                                                       int* __restrict__ deg) {
  const int g = blockIdx.x & (NRANGE - 1);
  const int tg = (blockIdx.x >> 3) * 256 + threadIdx.x;   // thread idx in group
  const int lo = g * RSPAN, hi = lo + RSPAN;
  for (int e = tg; e < ET; e += BPG * 256) {
    int d = (e < E_EDGES) ? ei[E_EDGES + e] : (e - E_EDGES);
    if (d >= lo && d < hi) atomicAdd(&deg[d], 1);
  }
}

__global__ __launch_bounds__(256) void scatter_part_kernel(const int* __restrict__ ei,
                                                           int* __restrict__ cursor,
                                                           int* __restrict__ csr_src) {
  const int g = blockIdx.x & (NRANGE - 1);
  const int tg = (blockIdx.x >> 3) * 256 + threadIdx.x;
  const int lo = g * RSPAN, hi = lo + RSPAN;
  for (int e = tg; e < ET; e += BPG * 256) {
    int d = (e < E_EDGES) ? ei[E_EDGES + e] : (e - E_EDGES);
    if (d >= lo && d < hi) {
      int s = (e < E_EDGES) ? ei[e] : d;
      int pos = atomicAdd(&cursor[d], 1);
      csr_src[pos] = s;
    }
  }
}

__global__ __launch_bounds__(256) void scan1_kernel(const int* __restrict__ deg,
                                                    int* __restrict__ exq,
                                                    int* __restrict__ bsum) {
  __shared__ int sh[256];
  const int t = threadIdx.x;
  const int idx = blockIdx.x * 256 + t;
  int v = (idx < N_NODES) ? deg[idx] : 0;
  sh[t] = v;
  __syncthreads();
  for (int off = 1; off < 256; off <<= 1) {
    int u = (t >= off) ? sh[t - off] : 0;
    __syncthreads();
    sh[t] += u;
    __syncthreads();
  }
  if (idx < N_NODES) exq[idx] = sh[t] - v;
  if (t == 255) bsum[blockIdx.x] = sh[t];
}

__global__ __launch_bounds__(256) void scan2_kernel(const int* __restrict__ bsum,
                                                    int* __restrict__ boff) {
  __shared__ int sh[256];
  const int t = threadIdx.x;
  int v = (t < NBLK) ? bsum[t] : 0;
  sh[t] = v;
  __syncthreads();
  for (int off = 1; off < 256; off <<= 1) {
    int u = (t >= off) ? sh[t - off] : 0;
    __syncthreads();
    sh[t] += u;
    __syncthreads();
  }
  if (t < NBLK) boff[t] = sh[t] - v;
}

__global__ __launch_bounds__(256) void scan3_kernel(const int* __restrict__ exq,
                                                    const int* __restrict__ boff,
                                                    int* __restrict__ rowptr,
                                                    int* __restrict__ cursor) {
  const int idx = blockIdx.x * 256 + threadIdx.x;
  if (idx < N_NODES) {
    int r = exq[idx] + boff[blockIdx.x];
    rowptr[idx] = r;
    cursor[idx] = r;
  }
  if (idx == 0) rowptr[N_NODES] = ET;
}

// ---------------- agg1: wave/dst; 16-edge unroll (2 dedup blocks in flight) -----
__global__ __launch_bounds__(256) void agg1_csr_kernel(const int* __restrict__ rowptr,
                                                       const int* __restrict__ csr_src,
                                                       const float* __restrict__ a_s,
                                                       const float* __restrict__ a_d,
                                                       const unsigned short* __restrict__ h1bf,
                                                       const float* __restrict__ b1,
                                                       unsigned short* __restrict__ out1bf) {
  int wid = (blockIdx.x * 256 + threadIdx.x) >> 6;
  int lane = threadIdx.x & 63;                   // lane owns feats 2*lane, 2*lane+1
  if (wid >= N_NODES) return;
  const int head = lane >> 3;                    // own head (feats) AND dedup edge slot
  const int sub = lane & 7;                      // dedup head index
  const float adn  = a_d[(size_t)wid * HEADS1 + head];
  const float adnb = a_d[(size_t)wid * HEADS1 + sub];
  int i = rowptr[wid], end = rowptr[wid + 1];
  float ax = 0.f, ay = 0.f, wsum = 0.f;
  for (; i + 15 < end; i += 16) {
    int sjA = csr_src[i + head];
    int sjB = csr_src[i + 8 + head];
    float wA = __expf(lrelu(a_s[(size_t)sjA * HEADS1 + sub] + adnb));
    float wB = __expf(lrelu(a_s[(size_t)sjB * HEADS1 + sub] + adnb));
    int sA[8], sB[8]; float wa[8], wb[8];
#pragma unroll
    for (int j = 0; j < 8; ++j) {
      sA[j] = __shfl(sjA, j * 8);  sB[j] = __shfl(sjB, j * 8);
      wa[j] = __shfl(wA, j * 8 + head);  wb[j] = __shfl(wB, j * 8 + head);
    }
    ushort2 gA[8], gB[8];
#pragma unroll
    for (int j = 0; j < 8; ++j) gA[j] = *(const ushort2*)&h1bf[(size_t)sA[j] * HID + 2 * lane];
#pragma unroll
    for (int j = 0; j < 8; ++j) gB[j] = *(const ushort2*)&h1bf[(size_t)sB[j] * HID + 2 * lane];
#pragma unroll
    for (int j = 0; j < 8; ++j) {
      ax += wa[j] * bf2f(gA[j].x) + wb[j] * bf2f(gB[j].x);
      ay += wa[j] * bf2f(gA[j].y) + wb[j] * bf2f(gB[j].y);
      wsum += wa[j] + wb[j];
    }
  }
  for (; i + 7 < end; i += 8) {
    int sj = csr_src[i + head];
    float w = __expf(lrelu(a_s[(size_t)sj * HEADS1 + sub] + adnb));
    int sarr[8]; float warr[8];
#pragma unroll
    for (int j = 0; j < 8; ++j) {
      sarr[j] = __shfl(sj, j * 8);
      warr[j] = __shfl(w, j * 8 + head);
    }
    ushort2 g[8];
#pragma unroll
    for (int j = 0; j < 8; ++j) g[j] = *(const ushort2*)&h1bf[(size_t)sarr[j] * HID + 2 * lane];
#pragma unroll
    for (int j = 0; j < 8; ++j) {
      ax += warr[j] * bf2f(g[j].x);
      ay += warr[j] * bf2f(g[j].y);
      wsum += warr[j];
    }
  }
  for (; i < end; ++i) {
    int s0 = csr_src[i];
    ushort2 g0 = *(const ushort2*)&h1bf[(size_t)s0 * HID + 2 * lane];
    float w0 = __expf(lrelu(a_s[(size_t)s0 * HEADS1 + head] + adn));
    ax += w0 * bf2f(g0.x); ay += w0 * bf2f(g0.y); wsum += w0;
  }
  float inv = 1.f / (wsum + 1e-16f);
  float vx = ax * inv + b1[2 * lane];
  float vy = ay * inv + b1[2 * lane + 1];
  vx = vx > 0.f ? vx : expm1f(vx);
  vy = vy > 0.f ? vy : expm1f(vy);
  ushort2 o; o.x = f2bf(vx); o.y = f2bf(vy);
  *(ushort2*)&out1bf[(size_t)wid * HID + 2 * lane] = o;
}

// ---------------- agg2: wave/dst; 16-edge unroll, dedup expf (lane&15) ----------
__global__ __launch_bounds__(256) void agg2_csr_kernel(const int* __restrict__ rowptr,
                                                       const int* __restrict__ csr_src,
                                                       const float* __restrict__ a_s,
                                                       const float* __restrict__ a_d,
                                                       const unsigned short* __restrict__ h2bf,
                                                       const float* __restrict__ b2,
                                                       float* __restrict__ out) {
  int wid = (blockIdx.x * 256 + threadIdx.x) >> 6;
  int lane = threadIdx.x & 63;                   // lane owns feat `lane`
  if (wid >= N_NODES) return;
  const float adn = a_d[wid];
  int i = rowptr[wid], end = rowptr[wid + 1];
  float acc = 0.f, wsum = 0.f;
  for (; i + 15 < end; i += 16) {
    int sme = csr_src[i + (lane & 15)];          // lanes 0-15 own edges 0-15
    float w = __expf(lrelu(a_s[sme] + adn));
    int sarr[16]; float warr[16];
#pragma unroll
    for (int j = 0; j < 16; ++j) { sarr[j] = __shfl(sme, j); warr[j] = __shfl(w, j); }
    unsigned short g[16];
#pragma unroll
    for (int j = 0; j < 16; ++j) g[j] = h2bf[(size_t)sarr[j] * OUT_F + lane];
#pragma unroll
    for (int j = 0; j < 16; ++j) { acc += warr[j] * bf2f(g[j]); wsum += warr[j]; }
  }
  for (; i + 7 < end; i += 8) {
    int sme = csr_src[i + (lane & 7)];
    float w = __expf(lrelu(a_s[sme] + adn));
    int sarr[8]; float warr[8];
#pragma unroll
    for (int j = 0; j < 8; ++j) { sarr[j] = __shfl(sme, j); warr[j] = __shfl(w, j); }
    unsigned short g[8];
#pragma unroll
    for (int j = 0; j < 8; ++j) g[j] = h2bf[(size_t)sarr[j] * OUT_F + lane];
#pragma unroll
    for (int j = 0; j < 8; ++j) { acc += warr[j] * bf2f(g[j]); wsum += warr[j]; }
  }
  for (; i < end; ++i) {
    int s0 = csr_src[i];
    float w0 = __expf(lrelu(a_s[s0] + adn));
    acc += w0 * bf2f(h2bf[(size_t)s0 * OUT_F + lane]);
    wsum += w0;
  }
  float v = acc / (wsum + 1e-16f) + b2[lane];
  float m = v;
#pragma unroll
  for (int msk = 1; msk < 64; msk <<= 1) m = fmaxf(m, __shfl_xor(m, msk));
  float sm = __expf(v - m);
#pragma unroll
  for (int msk = 1; msk < 64; msk <<= 1) sm += __shfl_xor(sm, msk);
  out[(size_t)wid * OUT_F + lane] = v - m - __logf(sm);
}

extern "C" void kernel_launch(void* const* d_in, const int* in_sizes, int n_in,
                              void* d_out, int out_size, void* d_ws, size_t ws_size,
                              hipStream_t stream) {
  const float* x   = (const float*)d_in[0];
  const int* ei    = (const int*)d_in[1];
  const float* W1  = (const float*)d_in[2];
  const float* as1 = (const float*)d_in[3];
  const float* ad1 = (const float*)d_in[4];
  const float* b1  = (const float*)d_in[5];
  const float* W2  = (const float*)d_in[6];
  const float* as2 = (const float*)d_in[7];
  const float* ad2 = (const float*)d_in[8];
  const float* b2  = (const float*)d_in[9];
  float* out = (float*)d_out;

  float* ws = (float*)d_ws;
  float* a_s1   = ws;  ws += (size_t)N_NODES * HEADS1;
  float* a_d1   = ws;  ws += (size_t)N_NODES * HEADS1;
  float* a_s2   = ws;  ws += (size_t)N_NODES;
  float* a_d2   = ws;  ws += (size_t)N_NODES;
  unsigned short* h1bf   = (unsigned short*)ws;  ws += (size_t)N_NODES * HID / 2;
  unsigned short* out1bf = (unsigned short*)ws;  ws += (size_t)N_NODES * HID / 2;
  unsigned short* h2bf   = (unsigned short*)ws;  ws += (size_t)N_NODES * OUT_F / 2;
  unsigned short* W1t = (unsigned short*)ws;  ws += (IN_F * HID) / 2;
  unsigned short* W2t = (unsigned short*)ws;  ws += (HID * OUT_F) / 2;
  int* deg      = (int*)ws;  ws += (N_NODES + 1);
  int* rowptr   = (int*)ws;  ws += (N_NODES + 1);
  int* cursor   = (int*)ws;  ws += N_NODES;
  int* csr_src  = (int*)ws;  ws += ET;
  int* exq      = (int*)ws;  ws += N_NODES;
  int* bsum     = (int*)ws;  ws += NBLK;
  int* boff     = (int*)ws;  ws += NBLK;

  // ---- weight transpose+cast (tiny; independent) ----
  wt_kernel<<<dim3((IN_F * HID + 255) / 256), dim3(256), 0, stream>>>(W1, W1t, IN_F, HID);
  wt_kernel<<<dim3((HID * OUT_F + 255) / 256), dim3(256), 0, stream>>>(W2, W2t, HID, OUT_F);

  // ---- CSR build (dst-range partitioned) ----
  hipMemsetAsync(deg, 0, sizeof(int) * (N_NODES + 1), stream);
  deg_part_kernel<<<dim3(NRANGE * BPG), dim3(256), 0, stream>>>(ei, deg);
  scan1_kernel<<<dim3(NBLK), dim3(256), 0, stream>>>(deg, exq, bsum);
  scan2_kernel<<<dim3(1), dim3(256), 0, stream>>>(bsum, boff);
  scan3_kernel<<<dim3(NBLK), dim3(256), 0, stream>>>(exq, boff, rowptr, cursor);
  scatter_part_kernel<<<dim3(NRANGE * BPG), dim3(256), 0, stream>>>(ei, cursor, csr_src);

  // ---- layer 1 ----
  gemm1_mfma_kernel<<<dim3((N_NODES + 63) / 64), dim3(256), 0, stream>>>(x, W1t, as1, ad1, h1bf, a_s1, a_d1);
  agg1_csr_kernel<<<dim3((N_NODES + 3) / 4), dim3(256), 0, stream>>>(rowptr, csr_src, a_s1, a_d1, h1bf, b1, out1bf);

  // ---- layer 2 ----
  gemm2_mfma_kernel<<<dim3((N_NODES + 63) / 64), dim3(256), 0, stream>>>(out1bf, W2t, as2, ad2, h2bf, a_s2, a_d2);
  agg2_csr_kernel<<<dim3((N_NODES + 3) / 4), dim3(256), 0, stream>>>(rowptr, csr_src, a_s2, a_d2, h2bf, b2, out);
}

// Round 9
// 314.942 us; speedup vs baseline: 1.0991x; 1.0991x over previous
//
#include <hip/hip_runtime.h>
#include <math.h>

#define N_NODES 50000
#define E_EDGES 800000
#define ET (E_EDGES + N_NODES)   // edges + self loops
#define IN_F 256
#define HID 128
#define HEADS1 8
#define C1 16
#define OUT_F 64
#define NEG_SLOPE 0.2f
#define NBLK ((N_NODES + 255) / 256)   // 196 scan blocks
#define NRANGE 8
#define RSPAN ((N_NODES + NRANGE - 1) / NRANGE)   // 6250
#define BPG 256                                    // blocks per range-group

typedef __attribute__((ext_vector_type(8))) short short8;
typedef __attribute__((ext_vector_type(4))) float float4v;

__device__ __forceinline__ float lrelu(float v) { return v > 0.f ? v : NEG_SLOPE * v; }

__device__ __forceinline__ unsigned short f2bf(float f) {
  union { float f; unsigned u; } v; v.f = f;
  unsigned r = v.u + 0x7FFF + ((v.u >> 16) & 1);   // RNE
  return (unsigned short)(r >> 16);
}
__device__ __forceinline__ float bf2f(unsigned short u) {
  union { unsigned u; float f; } v; v.u = ((unsigned)u) << 16; return v.f;
}

// ---- W transpose+cast: Wt[n][k] bf16 from W[k][n] fp32 ----
__global__ __launch_bounds__(256) void wt_kernel(const float* __restrict__ W,
                                                 unsigned short* __restrict__ Wt,
                                                 int K, int Nc) {
  int i = blockIdx.x * 256 + threadIdx.x;
  if (i >= K * Nc) return;
  int n = i / K, k = i - n * K;
  Wt[i] = f2bf(W[k * Nc + n]);
}

// ---------------- GEMM1 (MFMA) + fused att1 epilogue ----------------
__global__ __launch_bounds__(256) void gemm1_mfma_kernel(const float* __restrict__ x,
                                                         const unsigned short* __restrict__ W1t,
                                                         const float* __restrict__ att_src,
                                                         const float* __restrict__ att_dst,
                                                         unsigned short* __restrict__ h1bf,
                                                         float* __restrict__ a_s,
                                                         float* __restrict__ a_d) {
  const int wave = blockIdx.x * 4 + (threadIdx.x >> 6);
  const int lane = threadIdx.x & 63;
  const int m0 = wave * 16;
  if (m0 >= N_NODES) return;
  const int lm = lane & 15;
  const int quad = lane >> 4;
  const int mrow = m0 + lm;
  const bool valid = mrow < N_NODES;
  const float* arow = x + (size_t)mrow * IN_F;

  float4v acc[8];
#pragma unroll
  for (int nt = 0; nt < 8; ++nt) acc[nt] = (float4v){0.f, 0.f, 0.f, 0.f};

#pragma unroll
  for (int k0 = 0; k0 < IN_F; k0 += 32) {
    short8 a;
    if (valid) {
      float4 f0 = *(const float4*)(arow + k0 + quad * 8);
      float4 f1 = *(const float4*)(arow + k0 + quad * 8 + 4);
      a[0] = f2bf(f0.x); a[1] = f2bf(f0.y); a[2] = f2bf(f0.z); a[3] = f2bf(f0.w);
      a[4] = f2bf(f1.x); a[5] = f2bf(f1.y); a[6] = f2bf(f1.z); a[7] = f2bf(f1.w);
    } else {
      a = (short8){0, 0, 0, 0, 0, 0, 0, 0};
    }
#pragma unroll
    for (int nt = 0; nt < 8; ++nt) {
      short8 b = *(const short8*)&W1t[(size_t)(nt * 16 + lm) * IN_F + k0 + quad * 8];
      acc[nt] = __builtin_amdgcn_mfma_f32_16x16x32_bf16(a, b, acc[nt], 0, 0, 0);
    }
  }

#pragma unroll
  for (int nt = 0; nt < 8; ++nt) {
#pragma unroll
    for (int r = 0; r < 4; ++r) {
      int row = m0 + quad * 4 + r;
      if (row < N_NODES) h1bf[(size_t)row * HID + nt * 16 + lm] = f2bf(acc[nt][r]);
    }
  }

  // ---- fused att1: per-head dot over cols; reduce over lm (16 lanes) ----
  float asv[8], adv[8];
#pragma unroll
  for (int nt = 0; nt < 8; ++nt) { asv[nt] = att_src[nt * 16 + lm]; adv[nt] = att_dst[nt * 16 + lm]; }
#pragma unroll
  for (int r = 0; r < 4; ++r) {
    int row = m0 + quad * 4 + r;
    float s[8], d[8];
#pragma unroll
    for (int nt = 0; nt < 8; ++nt) { s[nt] = acc[nt][r] * asv[nt]; d[nt] = acc[nt][r] * adv[nt]; }
#pragma unroll
    for (int m = 1; m < 16; m <<= 1) {
#pragma unroll
      for (int nt = 0; nt < 8; ++nt) { s[nt] += __shfl_xor(s[nt], m); d[nt] += __shfl_xor(d[nt], m); }
    }
    if (lm == 0 && row < N_NODES) {
#pragma unroll
      for (int nt = 0; nt < 8; ++nt) {
        a_s[(size_t)row * HEADS1 + nt] = s[nt];
        a_d[(size_t)row * HEADS1 + nt] = d[nt];
      }
    }
  }
}

// ---------------- GEMM2 (MFMA) + fused att2 epilogue ----------------
__global__ __launch_bounds__(256) void gemm2_mfma_kernel(const unsigned short* __restrict__ in,
                                                         const unsigned short* __restrict__ W2t,
                                                         const float* __restrict__ att_src,
                                                         const float* __restrict__ att_dst,
                                                         unsigned short* __restrict__ h2bf,
                                                         float* __restrict__ a_s,
                                                         float* __restrict__ a_d) {
  const int wave = blockIdx.x * 4 + (threadIdx.x >> 6);
  const int lane = threadIdx.x & 63;
  const int m0 = wave * 16;
  if (m0 >= N_NODES) return;
  const int lm = lane & 15;
  const int quad = lane >> 4;
  const int mrow = m0 + lm;
  const bool valid = mrow < N_NODES;
  const unsigned short* arow = in + (size_t)mrow * HID;

  float4v acc[4];
#pragma unroll
  for (int nt = 0; nt < 4; ++nt) acc[nt] = (float4v){0.f, 0.f, 0.f, 0.f};

#pragma unroll
  for (int k0 = 0; k0 < HID; k0 += 32) {
    short8 a = valid ? *(const short8*)(arow + k0 + quad * 8)
                     : (short8){0, 0, 0, 0, 0, 0, 0, 0};
#pragma unroll
    for (int nt = 0; nt < 4; ++nt) {
      short8 b = *(const short8*)&W2t[(size_t)(nt * 16 + lm) * HID + k0 + quad * 8];
      acc[nt] = __builtin_amdgcn_mfma_f32_16x16x32_bf16(a, b, acc[nt], 0, 0, 0);
    }
  }

#pragma unroll
  for (int nt = 0; nt < 4; ++nt) {
#pragma unroll
    for (int r = 0; r < 4; ++r) {
      int row = m0 + quad * 4 + r;
      if (row < N_NODES) h2bf[(size_t)row * OUT_F + nt * 16 + lm] = f2bf(acc[nt][r]);
    }
  }

  // ---- fused att2: single head over 64 cols ----
  float as0 = att_src[lm], as1v = att_src[16 + lm], as2v = att_src[32 + lm], as3 = att_src[48 + lm];
  float ad0 = att_dst[lm], ad1v = att_dst[16 + lm], ad2v = att_dst[32 + lm], ad3 = att_dst[48 + lm];
#pragma unroll
  for (int r = 0; r < 4; ++r) {
    int row = m0 + quad * 4 + r;
    float s = acc[0][r] * as0 + acc[1][r] * as1v + acc[2][r] * as2v + acc[3][r] * as3;
    float d = acc[0][r] * ad0 + acc[1][r] * ad1v + acc[2][r] * ad2v + acc[3][r] * ad3;
#pragma unroll
    for (int m = 1; m < 16; m <<= 1) { s += __shfl_xor(s, m); d += __shfl_xor(d, m); }
    if (lm == 0 && row < N_NODES) { a_s[row] = s; a_d[row] = d; }
  }
}

// ---------------- CSR construction (dst-range partitioned for L2 locality) ------
__global__ __launch_bounds__(256) void deg_part_kernel(const int* __restrict__ ei,
                                                       int* __restrict__ deg) {
  const int g = blockIdx.x & (NRANGE - 1);
  const int tg = (blockIdx.x >> 3) * 256 + threadIdx.x;   // thread idx in group
  const int lo = g * RSPAN, hi = lo + RSPAN;
  for (int e = tg; e < ET; e += BPG * 256) {
    int d = (e < E_EDGES) ? ei[E_EDGES + e] : (e - E_EDGES);
    if (d >= lo && d < hi) atomicAdd(&deg[d], 1);
  }
}

__global__ __launch_bounds__(256) void scatter_part_kernel(const int* __restrict__ ei,
                                                           int* __restrict__ cursor,
                                                           int* __restrict__ csr_src) {
  const int g = blockIdx.x & (NRANGE - 1);
  const int tg = (blockIdx.x >> 3) * 256 + threadIdx.x;
  const int lo = g * RSPAN, hi = lo + RSPAN;
  for (int e = tg; e < ET; e += BPG * 256) {
    int d = (e < E_EDGES) ? ei[E_EDGES + e] : (e - E_EDGES);
    if (d >= lo && d < hi) {
      int s = (e < E_EDGES) ? ei[e] : d;
      int pos = atomicAdd(&cursor[d], 1);
      csr_src[pos] = s;
    }
  }
}

__global__ __launch_bounds__(256) void scan1_kernel(const int* __restrict__ deg,
                                                    int* __restrict__ exq,
                                                    int* __restrict__ bsum) {
  __shared__ int sh[256];
  const int t = threadIdx.x;
  const int idx = blockIdx.x * 256 + t;
  int v = (idx < N_NODES) ? deg[idx] : 0;
  sh[t] = v;
  __syncthreads();
  for (int off = 1; off < 256; off <<= 1) {
    int u = (t >= off) ? sh[t - off] : 0;
    __syncthreads();
    sh[t] += u;
    __syncthreads();
  }
  if (idx < N_NODES) exq[idx] = sh[t] - v;
  if (t == 255) bsum[blockIdx.x] = sh[t];
}

__global__ __launch_bounds__(256) void scan2_kernel(const int* __restrict__ bsum,
                                                    int* __restrict__ boff) {
  __shared__ int sh[256];
  const int t = threadIdx.x;
  int v = (t < NBLK) ? bsum[t] : 0;
  sh[t] = v;
  __syncthreads();
  for (int off = 1; off < 256; off <<= 1) {
    int u = (t >= off) ? sh[t - off] : 0;
    __syncthreads();
    sh[t] += u;
    __syncthreads();
  }
  if (t < NBLK) boff[t] = sh[t] - v;
}

__global__ __launch_bounds__(256) void scan3_kernel(const int* __restrict__ exq,
                                                    const int* __restrict__ boff,
                                                    int* __restrict__ rowptr,
                                                    int* __restrict__ cursor) {
  const int idx = blockIdx.x * 256 + threadIdx.x;
  if (idx < N_NODES) {
    int r = exq[idx] + boff[blockIdx.x];
    rowptr[idx] = r;
    cursor[idx] = r;
  }
  if (idx == 0) rowptr[N_NODES] = ET;
}

// ---------------- agg1: wave/dst; 16-lane×16B row gathers (4 edges/instr) -------
// Lane layout: fl=lane&15 owns feats [8*fl, 8*fl+8) (single head fl>>1);
// g=lane>>4 is the edge-group. One short8 load gathers 4 edges' rows at once.
// Tail edges neutralized with w=0 (no divergence). One butterfly per node.
__global__ __launch_bounds__(256) void agg1_csr_kernel(const int* __restrict__ rowptr,
                                                       const int* __restrict__ csr_src,
                                                       const float* __restrict__ a_s,
                                                       const float* __restrict__ a_d,
                                                       const unsigned short* __restrict__ h1bf,
                                                       const float* __restrict__ b1,
                                                       unsigned short* __restrict__ out1bf) {
  int wid = (blockIdx.x * 256 + threadIdx.x) >> 6;
  int lane = threadIdx.x & 63;
  if (wid >= N_NODES) return;
  const int fl = lane & 15;
  const int g  = lane >> 4;
  const int myh = fl >> 1;
  const float adn = a_d[(size_t)wid * HEADS1 + myh];
  const int start = rowptr[wid], end = rowptr[wid + 1];
  float acc[8];
#pragma unroll
  for (int k = 0; k < 8; ++k) acc[k] = 0.f;
  float wsum = 0.f;

  for (int i = start; i < end; i += 8) {
    int e0 = i + g, e1 = i + 4 + g;
    bool v0 = e0 < end, v1 = e1 < end;
    int s0 = csr_src[v0 ? e0 : start];
    int s1 = csr_src[v1 ? e1 : start];
    float l0 = a_s[(size_t)s0 * HEADS1 + myh];
    float l1 = a_s[(size_t)s1 * HEADS1 + myh];
    short8 r0 = *(const short8*)&h1bf[(size_t)s0 * HID + fl * 8];
    short8 r1 = *(const short8*)&h1bf[(size_t)s1 * HID + fl * 8];
    float w0 = v0 ? __expf(lrelu(l0 + adn)) : 0.f;
    float w1 = v1 ? __expf(lrelu(l1 + adn)) : 0.f;
#pragma unroll
    for (int k = 0; k < 8; ++k)
      acc[k] += w0 * bf2f((unsigned short)r0[k]) + w1 * bf2f((unsigned short)r1[k]);
    wsum += w0 + w1;
  }

  // cross-group butterfly (groups differ by lane bits 4,5)
#pragma unroll
  for (int k = 0; k < 8; ++k) {
    acc[k] += __shfl_xor(acc[k], 16);
    acc[k] += __shfl_xor(acc[k], 32);
  }
  wsum += __shfl_xor(wsum, 16);
  wsum += __shfl_xor(wsum, 32);

  if (g == 0) {
    float inv = 1.f / (wsum + 1e-16f);
    float4 blo = *(const float4*)&b1[fl * 8];
    float4 bhi = *(const float4*)&b1[fl * 8 + 4];
    float vv[8];
    vv[0] = acc[0] * inv + blo.x; vv[1] = acc[1] * inv + blo.y;
    vv[2] = acc[2] * inv + blo.z; vv[3] = acc[3] * inv + blo.w;
    vv[4] = acc[4] * inv + bhi.x; vv[5] = acc[5] * inv + bhi.y;
    vv[6] = acc[6] * inv + bhi.z; vv[7] = acc[7] * inv + bhi.w;
    short8 o;
#pragma unroll
    for (int k = 0; k < 8; ++k) {
      float e = vv[k] > 0.f ? vv[k] : expm1f(vv[k]);
      o[k] = (short)f2bf(e);
    }
    *(short8*)&out1bf[(size_t)wid * HID + fl * 8] = o;
  }
}

// ---------------- agg2: wave/dst; 8-lane×16B row gathers (8 edges/instr) --------
__global__ __launch_bounds__(256) void agg2_csr_kernel(const int* __restrict__ rowptr,
                                                       const int* __restrict__ csr_src,
                                                       const float* __restrict__ a_s,
                                                       const float* __restrict__ a_d,
                                                       const unsigned short* __restrict__ h2bf,
                                                       const float* __restrict__ b2,
                                                       float* __restrict__ out) {
  int wid = (blockIdx.x * 256 + threadIdx.x) >> 6;
  int lane = threadIdx.x & 63;
  if (wid >= N_NODES) return;
  const int fl = lane & 7;       // owns feats [8*fl, 8*fl+8)
  const int g  = lane >> 3;      // edge group 0..7
  const float adn = a_d[wid];
  const int start = rowptr[wid], end = rowptr[wid + 1];
  float acc[8];
#pragma unroll
  for (int k = 0; k < 8; ++k) acc[k] = 0.f;
  float wsum = 0.f;

  for (int i = start; i < end; i += 16) {
    int e0 = i + g, e1 = i + 8 + g;
    bool v0 = e0 < end, v1 = e1 < end;
    int s0 = csr_src[v0 ? e0 : start];
    int s1 = csr_src[v1 ? e1 : start];
    float l0 = a_s[s0];
    float l1 = a_s[s1];
    short8 r0 = *(const short8*)&h2bf[(size_t)s0 * OUT_F + fl * 8];
    short8 r1 = *(const short8*)&h2bf[(size_t)s1 * OUT_F + fl * 8];
    float w0 = v0 ? __expf(lrelu(l0 + adn)) : 0.f;
    float w1 = v1 ? __expf(lrelu(l1 + adn)) : 0.f;
#pragma unroll
    for (int k = 0; k < 8; ++k)
      acc[k] += w0 * bf2f((unsigned short)r0[k]) + w1 * bf2f((unsigned short)r1[k]);
    wsum += w0 + w1;
  }

  // cross-group butterfly (groups differ by lane bits 3,4,5)
#pragma unroll
  for (int k = 0; k < 8; ++k) {
    acc[k] += __shfl_xor(acc[k], 8);
    acc[k] += __shfl_xor(acc[k], 16);
    acc[k] += __shfl_xor(acc[k], 32);
  }
  wsum += __shfl_xor(wsum, 8);
  wsum += __shfl_xor(wsum, 16);
  wsum += __shfl_xor(wsum, 32);

  // log_softmax over the 64 feats (distributed over fl groups; all g identical)
  float inv = 1.f / (wsum + 1e-16f);
  float4 blo = *(const float4*)&b2[fl * 8];
  float4 bhi = *(const float4*)&b2[fl * 8 + 4];
  float vv[8];
  vv[0] = acc[0] * inv + blo.x; vv[1] = acc[1] * inv + blo.y;
  vv[2] = acc[2] * inv + blo.z; vv[3] = acc[3] * inv + blo.w;
  vv[4] = acc[4] * inv + bhi.x; vv[5] = acc[5] * inv + bhi.y;
  vv[6] = acc[6] * inv + bhi.z; vv[7] = acc[7] * inv + bhi.w;
  float m = vv[0];
#pragma unroll
  for (int k = 1; k < 8; ++k) m = fmaxf(m, vv[k]);
#pragma unroll
  for (int msk = 1; msk < 8; msk <<= 1) m = fmaxf(m, __shfl_xor(m, msk));
  float sm = 0.f;
#pragma unroll
  for (int k = 0; k < 8; ++k) sm += __expf(vv[k] - m);
#pragma unroll
  for (int msk = 1; msk < 8; msk <<= 1) sm += __shfl_xor(sm, msk);
  float lse = m + __logf(sm);
  if (g == 0) {
    float4 o0 = make_float4(vv[0] - lse, vv[1] - lse, vv[2] - lse, vv[3] - lse);
    float4 o1 = make_float4(vv[4] - lse, vv[5] - lse, vv[6] - lse, vv[7] - lse);
    *(float4*)&out[(size_t)wid * OUT_F + fl * 8]     = o0;
    *(float4*)&out[(size_t)wid * OUT_F + fl * 8 + 4] = o1;
  }
}

extern "C" void kernel_launch(void* const* d_in, const int* in_sizes, int n_in,
                              void* d_out, int out_size, void* d_ws, size_t ws_size,
                              hipStream_t stream) {
  const float* x   = (const float*)d_in[0];
  const int* ei    = (const int*)d_in[1];
  const float* W1  = (const float*)d_in[2];
  const float* as1 = (const float*)d_in[3];
  const float* ad1 = (const float*)d_in[4];
  const float* b1  = (const float*)d_in[5];
  const float* W2  = (const float*)d_in[6];
  const float* as2 = (const float*)d_in[7];
  const float* ad2 = (const float*)d_in[8];
  const float* b2  = (const float*)d_in[9];
  float* out = (float*)d_out;

  float* ws = (float*)d_ws;
  float* a_s1   = ws;  ws += (size_t)N_NODES * HEADS1;
  float* a_d1   = ws;  ws += (size_t)N_NODES * HEADS1;
  float* a_s2   = ws;  ws += (size_t)N_NODES;
  float* a_d2   = ws;  ws += (size_t)N_NODES;
  unsigned short* h1bf   = (unsigned short*)ws;  ws += (size_t)N_NODES * HID / 2;
  unsigned short* out1bf = (unsigned short*)ws;  ws += (size_t)N_NODES * HID / 2;
  unsigned short* h2bf   = (unsigned short*)ws;  ws += (size_t)N_NODES * OUT_F / 2;
  unsigned short* W1t = (unsigned short*)ws;  ws += (IN_F * HID) / 2;
  unsigned short* W2t = (unsigned short*)ws;  ws += (HID * OUT_F) / 2;
  int* deg      = (int*)ws;  ws += (N_NODES + 1);
  int* rowptr   = (int*)ws;  ws += (N_NODES + 1);
  int* cursor   = (int*)ws;  ws += N_NODES;
  int* csr_src  = (int*)ws;  ws += ET;
  int* exq      = (int*)ws;  ws += N_NODES;
  int* bsum     = (int*)ws;  ws += NBLK;
  int* boff     = (int*)ws;  ws += NBLK;

  // ---- weight transpose+cast (tiny; independent) ----
  wt_kernel<<<dim3((IN_F * HID + 255) / 256), dim3(256), 0, stream>>>(W1, W1t, IN_F, HID);
  wt_kernel<<<dim3((HID * OUT_F + 255) / 256), dim3(256), 0, stream>>>(W2, W2t, HID, OUT_F);

  // ---- CSR build (dst-range partitioned) ----
  hipMemsetAsync(deg, 0, sizeof(int) * (N_NODES + 1), stream);
  deg_part_kernel<<<dim3(NRANGE * BPG), dim3(256), 0, stream>>>(ei, deg);
  scan1_kernel<<<dim3(NBLK), dim3(256), 0, stream>>>(deg, exq, bsum);
  scan2_kernel<<<dim3(1), dim3(256), 0, stream>>>(bsum, boff);
  scan3_kernel<<<dim3(NBLK), dim3(256), 0, stream>>>(exq, boff, rowptr, cursor);
  scatter_part_kernel<<<dim3(NRANGE * BPG), dim3(256), 0, stream>>>(ei, cursor, csr_src);

  // ---- layer 1 ----
  gemm1_mfma_kernel<<<dim3((N_NODES + 63) / 64), dim3(256), 0, stream>>>(x, W1t, as1, ad1, h1bf, a_s1, a_d1);
  agg1_csr_kernel<<<dim3((N_NODES + 3) / 4), dim3(256), 0, stream>>>(rowptr, csr_src, a_s1, a_d1, h1bf, b1, out1bf);

  // ---- layer 2 ----
  gemm2_mfma_kernel<<<dim3((N_NODES + 63) / 64), dim3(256), 0, stream>>>(out1bf, W2t, as2, ad2, h2bf, a_s2, a_d2);
  agg2_csr_kernel<<<dim3((N_NODES + 3) / 4), dim3(256), 0, stream>>>(rowptr, csr_src, a_s2, a_d2, h2bf, b2, out);
}

// Round 10
// 311.924 us; speedup vs baseline: 1.1098x; 1.0097x over previous
//
#include <hip/hip_runtime.h>
#include <math.h>

#define N_NODES 50000
#define E_EDGES 800000
#define ET (E_EDGES + N_NODES)   // edges + self loops
#define IN_F 256
#define HID 128
#define HEADS1 8
#define C1 16
#define OUT_F 64
#define NEG_SLOPE 0.2f
#define NBLK ((N_NODES + 255) / 256)   // 196 scan blocks
#define NRANGE 8
#define RSPAN ((N_NODES + NRANGE - 1) / NRANGE)   // 6250
#define BPG 256                                    // blocks per range-group

typedef __attribute__((ext_vector_type(8))) short short8;
typedef __attribute__((ext_vector_type(4))) float float4v;

__device__ __forceinline__ float lrelu(float v) { return v > 0.f ? v : NEG_SLOPE * v; }

__device__ __forceinline__ unsigned short f2bf(float f) {
  union { float f; unsigned u; } v; v.f = f;
  unsigned r = v.u + 0x7FFF + ((v.u >> 16) & 1);   // RNE
  return (unsigned short)(r >> 16);
}
__device__ __forceinline__ float bf2f(unsigned short u) {
  union { unsigned u; float f; } v; v.u = ((unsigned)u) << 16; return v.f;
}

// ---- W transpose+cast: Wt[n][k] bf16 from W[k][n] fp32 ----
__global__ __launch_bounds__(256) void wt_kernel(const float* __restrict__ W,
                                                 unsigned short* __restrict__ Wt,
                                                 int K, int Nc) {
  int i = blockIdx.x * 256 + threadIdx.x;
  if (i >= K * Nc) return;
  int n = i / K, k = i - n * K;
  Wt[i] = f2bf(W[k * Nc + n]);
}

// ---------------- GEMM1 (MFMA) + fused att1 epilogue, N-split 2x ----------------
// blockIdx: bit0 = col-half (64 cols = heads 4h..4h+3), rest = 64-row block.
// 2x waves vs round 9 -> double the independent A-load chains per CU (latency fix).
__global__ __launch_bounds__(256) void gemm1_mfma_kernel(const float* __restrict__ x,
                                                         const unsigned short* __restrict__ W1t,
                                                         const float* __restrict__ att_src,
                                                         const float* __restrict__ att_dst,
                                                         unsigned short* __restrict__ h1bf,
                                                         float* __restrict__ a_s,
                                                         float* __restrict__ a_d) {
  const int ch = blockIdx.x & 1;                  // col half
  const int rb = blockIdx.x >> 1;                 // 64-row block
  const int wave = rb * 4 + (threadIdx.x >> 6);
  const int lane = threadIdx.x & 63;
  const int m0 = wave * 16;
  if (m0 >= N_NODES) return;
  const int lm = lane & 15;
  const int quad = lane >> 4;
  const int mrow = m0 + lm;
  const bool valid = mrow < N_NODES;
  const float* arow = x + (size_t)mrow * IN_F;
  const int c0 = ch * 64;                         // col base

  float4v acc[4];
#pragma unroll
  for (int nt = 0; nt < 4; ++nt) acc[nt] = (float4v){0.f, 0.f, 0.f, 0.f};

#pragma unroll
  for (int k0 = 0; k0 < IN_F; k0 += 32) {
    short8 a;
    if (valid) {
      float4 f0 = *(const float4*)(arow + k0 + quad * 8);
      float4 f1 = *(const float4*)(arow + k0 + quad * 8 + 4);
      a[0] = f2bf(f0.x); a[1] = f2bf(f0.y); a[2] = f2bf(f0.z); a[3] = f2bf(f0.w);
      a[4] = f2bf(f1.x); a[5] = f2bf(f1.y); a[6] = f2bf(f1.z); a[7] = f2bf(f1.w);
    } else {
      a = (short8){0, 0, 0, 0, 0, 0, 0, 0};
    }
#pragma unroll
    for (int nt = 0; nt < 4; ++nt) {
      short8 b = *(const short8*)&W1t[(size_t)(c0 + nt * 16 + lm) * IN_F + k0 + quad * 8];
      acc[nt] = __builtin_amdgcn_mfma_f32_16x16x32_bf16(a, b, acc[nt], 0, 0, 0);
    }
  }

#pragma unroll
  for (int nt = 0; nt < 4; ++nt) {
#pragma unroll
    for (int r = 0; r < 4; ++r) {
      int row = m0 + quad * 4 + r;
      if (row < N_NODES) h1bf[(size_t)row * HID + c0 + nt * 16 + lm] = f2bf(acc[nt][r]);
    }
  }

  // ---- fused att1: this wave owns heads ch*4 + nt (complete 16-col groups) ----
  float asv[4], adv[4];
#pragma unroll
  for (int nt = 0; nt < 4; ++nt) {
    asv[nt] = att_src[c0 + nt * 16 + lm];
    adv[nt] = att_dst[c0 + nt * 16 + lm];
  }
#pragma unroll
  for (int r = 0; r < 4; ++r) {
    int row = m0 + quad * 4 + r;
    float s[4], d[4];
#pragma unroll
    for (int nt = 0; nt < 4; ++nt) { s[nt] = acc[nt][r] * asv[nt]; d[nt] = acc[nt][r] * adv[nt]; }
#pragma unroll
    for (int m = 1; m < 16; m <<= 1) {
#pragma unroll
      for (int nt = 0; nt < 4; ++nt) { s[nt] += __shfl_xor(s[nt], m); d[nt] += __shfl_xor(d[nt], m); }
    }
    if (lm == 0 && row < N_NODES) {
#pragma unroll
      for (int nt = 0; nt < 4; ++nt) {
        a_s[(size_t)row * HEADS1 + ch * 4 + nt] = s[nt];
        a_d[(size_t)row * HEADS1 + ch * 4 + nt] = d[nt];
      }
    }
  }
}

// ---------------- GEMM2 (MFMA) + fused att2 epilogue ----------------
__global__ __launch_bounds__(256) void gemm2_mfma_kernel(const unsigned short* __restrict__ in,
                                                         const unsigned short* __restrict__ W2t,
                                                         const float* __restrict__ att_src,
                                                         const float* __restrict__ att_dst,
                                                         unsigned short* __restrict__ h2bf,
                                                         float* __restrict__ a_s,
                                                         float* __restrict__ a_d) {
  const int wave = blockIdx.x * 4 + (threadIdx.x >> 6);
  const int lane = threadIdx.x & 63;
  const int m0 = wave * 16;
  if (m0 >= N_NODES) return;
  const int lm = lane & 15;
  const int quad = lane >> 4;
  const int mrow = m0 + lm;
  const bool valid = mrow < N_NODES;
  const unsigned short* arow = in + (size_t)mrow * HID;

  float4v acc[4];
#pragma unroll
  for (int nt = 0; nt < 4; ++nt) acc[nt] = (float4v){0.f, 0.f, 0.f, 0.f};

#pragma unroll
  for (int k0 = 0; k0 < HID; k0 += 32) {
    short8 a = valid ? *(const short8*)(arow + k0 + quad * 8)
                     : (short8){0, 0, 0, 0, 0, 0, 0, 0};
#pragma unroll
    for (int nt = 0; nt < 4; ++nt) {
      short8 b = *(const short8*)&W2t[(size_t)(nt * 16 + lm) * HID + k0 + quad * 8];
      acc[nt] = __builtin_amdgcn_mfma_f32_16x16x32_bf16(a, b, acc[nt], 0, 0, 0);
    }
  }

#pragma unroll
  for (int nt = 0; nt < 4; ++nt) {
#pragma unroll
    for (int r = 0; r < 4; ++r) {
      int row = m0 + quad * 4 + r;
      if (row < N_NODES) h2bf[(size_t)row * OUT_F + nt * 16 + lm] = f2bf(acc[nt][r]);
    }
  }

  // ---- fused att2: single head over 64 cols ----
  float as0 = att_src[lm], as1v = att_src[16 + lm], as2v = att_src[32 + lm], as3 = att_src[48 + lm];
  float ad0 = att_dst[lm], ad1v = att_dst[16 + lm], ad2v = att_dst[32 + lm], ad3 = att_dst[48 + lm];
#pragma unroll
  for (int r = 0; r < 4; ++r) {
    int row = m0 + quad * 4 + r;
    float s = acc[0][r] * as0 + acc[1][r] * as1v + acc[2][r] * as2v + acc[3][r] * as3;
    float d = acc[0][r] * ad0 + acc[1][r] * ad1v + acc[2][r] * ad2v + acc[3][r] * ad3;
#pragma unroll
    for (int m = 1; m < 16; m <<= 1) { s += __shfl_xor(s, m); d += __shfl_xor(d, m); }
    if (lm == 0 && row < N_NODES) { a_s[row] = s; a_d[row] = d; }
  }
}

// ---------------- CSR construction (dst-range partitioned for L2 locality) ------
__global__ __launch_bounds__(256) void deg_part_kernel(const int* __restrict__ ei,
                                                       int* __restrict__ deg) {
  const int g = blockIdx.x & (NRANGE - 1);
  const int tg = (blockIdx.x >> 3) * 256 + threadIdx.x;   // thread idx in group
  const int lo = g * RSPAN, hi = lo + RSPAN;
  for (int e = tg; e < ET; e += BPG * 256) {
    int d = (e < E_EDGES) ? ei[E_EDGES + e] : (e - E_EDGES);
    if (d >= lo && d < hi) atomicAdd(&deg[d], 1);
  }
}

__global__ __launch_bounds__(256) void scatter_part_kernel(const int* __restrict__ ei,
                                                           int* __restrict__ cursor,
                                                           int* __restrict__ csr_src) {
  const int g = blockIdx.x & (NRANGE - 1);
  const int tg = (blockIdx.x >> 3) * 256 + threadIdx.x;
  const int lo = g * RSPAN, hi = lo + RSPAN;
  for (int e = tg; e < ET; e += BPG * 256) {
    int d = (e < E_EDGES) ? ei[E_EDGES + e] : (e - E_EDGES);
    if (d >= lo && d < hi) {
      int s = (e < E_EDGES) ? ei[e] : d;
      int pos = atomicAdd(&cursor[d], 1);
      csr_src[pos] = s;
    }
  }
}

__global__ __launch_bounds__(256) void scan1_kernel(const int* __restrict__ deg,
                                                    int* __restrict__ exq,
                                                    int* __restrict__ bsum) {
  __shared__ int sh[256];
  const int t = threadIdx.x;
  const int idx = blockIdx.x * 256 + t;
  int v = (idx < N_NODES) ? deg[idx] : 0;
  sh[t] = v;
  __syncthreads();
  for (int off = 1; off < 256; off <<= 1) {
    int u = (t >= off) ? sh[t - off] : 0;
    __syncthreads();
    sh[t] += u;
    __syncthreads();
  }
  if (idx < N_NODES) exq[idx] = sh[t] - v;
  if (t == 255) bsum[blockIdx.x] = sh[t];
}

__global__ __launch_bounds__(256) void scan2_kernel(const int* __restrict__ bsum,
                                                    int* __restrict__ boff) {
  __shared__ int sh[256];
  const int t = threadIdx.x;
  int v = (t < NBLK) ? bsum[t] : 0;
  sh[t] = v;
  __syncthreads();
  for (int off = 1; off < 256; off <<= 1) {
    int u = (t >= off) ? sh[t - off] : 0;
    __syncthreads();
    sh[t] += u;
    __syncthreads();
  }
  if (t < NBLK) boff[t] = sh[t] - v;
}

__global__ __launch_bounds__(256) void scan3_kernel(const int* __restrict__ exq,
                                                    const int* __restrict__ boff,
                                                    int* __restrict__ rowptr,
                                                    int* __restrict__ cursor) {
  const int idx = blockIdx.x * 256 + threadIdx.x;
  if (idx < N_NODES) {
    int r = exq[idx] + boff[blockIdx.x];
    rowptr[idx] = r;
    cursor[idx] = r;
  }
  if (idx == 0) rowptr[N_NODES] = ET;
}

// ---------------- agg1: wave/dst; 16-lane×16B row gathers (4 edges/instr) -------
__global__ __launch_bounds__(256) void agg1_csr_kernel(const int* __restrict__ rowptr,
                                                       const int* __restrict__ csr_src,
                                                       const float* __restrict__ a_s,
                                                       const float* __restrict__ a_d,
                                                       const unsigned short* __restrict__ h1bf,
                                                       const float* __restrict__ b1,
                                                       unsigned short* __restrict__ out1bf) {
  int wid = (blockIdx.x * 256 + threadIdx.x) >> 6;
  int lane = threadIdx.x & 63;
  if (wid >= N_NODES) return;
  const int fl = lane & 15;
  const int g  = lane >> 4;
  const int myh = fl >> 1;
  const float adn = a_d[(size_t)wid * HEADS1 + myh];
  const int start = rowptr[wid], end = rowptr[wid + 1];
  float acc[8];
#pragma unroll
  for (int k = 0; k < 8; ++k) acc[k] = 0.f;
  float wsum = 0.f;

  for (int i = start; i < end; i += 8) {
    int e0 = i + g, e1 = i + 4 + g;
    bool v0 = e0 < end, v1 = e1 < end;
    int s0 = csr_src[v0 ? e0 : start];
    int s1 = csr_src[v1 ? e1 : start];
    float l0 = a_s[(size_t)s0 * HEADS1 + myh];
    float l1 = a_s[(size_t)s1 * HEADS1 + myh];
    short8 r0 = *(const short8*)&h1bf[(size_t)s0 * HID + fl * 8];
    short8 r1 = *(const short8*)&h1bf[(size_t)s1 * HID + fl * 8];
    float w0 = v0 ? __expf(lrelu(l0 + adn)) : 0.f;
    float w1 = v1 ? __expf(lrelu(l1 + adn)) : 0.f;
#pragma unroll
    for (int k = 0; k < 8; ++k)
      acc[k] += w0 * bf2f((unsigned short)r0[k]) + w1 * bf2f((unsigned short)r1[k]);
    wsum += w0 + w1;
  }

#pragma unroll
  for (int k = 0; k < 8; ++k) {
    acc[k] += __shfl_xor(acc[k], 16);
    acc[k] += __shfl_xor(acc[k], 32);
  }
  wsum += __shfl_xor(wsum, 16);
  wsum += __shfl_xor(wsum, 32);

  if (g == 0) {
    float inv = 1.f / (wsum + 1e-16f);
    float4 blo = *(const float4*)&b1[fl * 8];
    float4 bhi = *(const float4*)&b1[fl * 8 + 4];
    float vv[8];
    vv[0] = acc[0] * inv + blo.x; vv[1] = acc[1] * inv + blo.y;
    vv[2] = acc[2] * inv + blo.z; vv[3] = acc[3] * inv + blo.w;
    vv[4] = acc[4] * inv + bhi.x; vv[5] = acc[5] * inv + bhi.y;
    vv[6] = acc[6] * inv + bhi.z; vv[7] = acc[7] * inv + bhi.w;
    short8 o;
#pragma unroll
    for (int k = 0; k < 8; ++k) {
      float e = vv[k] > 0.f ? vv[k] : expm1f(vv[k]);
      o[k] = (short)f2bf(e);
    }
    *(short8*)&out1bf[(size_t)wid * HID + fl * 8] = o;
  }
}

// ---------------- agg2: wave/dst; 8-lane×16B row gathers (8 edges/instr) --------
__global__ __launch_bounds__(256) void agg2_csr_kernel(const int* __restrict__ rowptr,
                                                       const int* __restrict__ csr_src,
                                                       const float* __restrict__ a_s,
                                                       const float* __restrict__ a_d,
                                                       const unsigned short* __restrict__ h2bf,
                                                       const float* __restrict__ b2,
                                                       float* __restrict__ out) {
  int wid = (blockIdx.x * 256 + threadIdx.x) >> 6;
  int lane = threadIdx.x & 63;
  if (wid >= N_NODES) return;
  const int fl = lane & 7;       // owns feats [8*fl, 8*fl+8)
  const int g  = lane >> 3;      // edge group 0..7
  const float adn = a_d[wid];
  const int start = rowptr[wid], end = rowptr[wid + 1];
  float acc[8];
#pragma unroll
  for (int k = 0; k < 8; ++k) acc[k] = 0.f;
  float wsum = 0.f;

  for (int i = start; i < end; i += 16) {
    int e0 = i + g, e1 = i + 8 + g;
    bool v0 = e0 < end, v1 = e1 < end;
    int s0 = csr_src[v0 ? e0 : start];
    int s1 = csr_src[v1 ? e1 : start];
    float l0 = a_s[s0];
    float l1 = a_s[s1];
    short8 r0 = *(const short8*)&h2bf[(size_t)s0 * OUT_F + fl * 8];
    short8 r1 = *(const short8*)&h2bf[(size_t)s1 * OUT_F + fl * 8];
    float w0 = v0 ? __expf(lrelu(l0 + adn)) : 0.f;
    float w1 = v1 ? __expf(lrelu(l1 + adn)) : 0.f;
#pragma unroll
    for (int k = 0; k < 8; ++k)
      acc[k] += w0 * bf2f((unsigned short)r0[k]) + w1 * bf2f((unsigned short)r1[k]);
    wsum += w0 + w1;
  }

#pragma unroll
  for (int k = 0; k < 8; ++k) {
    acc[k] += __shfl_xor(acc[k], 8);
    acc[k] += __shfl_xor(acc[k], 16);
    acc[k] += __shfl_xor(acc[k], 32);
  }
  wsum += __shfl_xor(wsum, 8);
  wsum += __shfl_xor(wsum, 16);
  wsum += __shfl_xor(wsum, 32);

  float inv = 1.f / (wsum + 1e-16f);
  float4 blo = *(const float4*)&b2[fl * 8];
  float4 bhi = *(const float4*)&b2[fl * 8 + 4];
  float vv[8];
  vv[0] = acc[0] * inv + blo.x; vv[1] = acc[1] * inv + blo.y;
  vv[2] = acc[2] * inv + blo.z; vv[3] = acc[3] * inv + blo.w;
  vv[4] = acc[4] * inv + bhi.x; vv[5] = acc[5] * inv + bhi.y;
  vv[6] = acc[6] * inv + bhi.z; vv[7] = acc[7] * inv + bhi.w;
  float m = vv[0];
#pragma unroll
  for (int k = 1; k < 8; ++k) m = fmaxf(m, vv[k]);
#pragma unroll
  for (int msk = 1; msk < 8; msk <<= 1) m = fmaxf(m, __shfl_xor(m, msk));
  float sm = 0.f;
#pragma unroll
  for (int k = 0; k < 8; ++k) sm += __expf(vv[k] - m);
#pragma unroll
  for (int msk = 1; msk < 8; msk <<= 1) sm += __shfl_xor(sm, msk);
  float lse = m + __logf(sm);
  if (g == 0) {
    float4 o0 = make_float4(vv[0] - lse, vv[1] - lse, vv[2] - lse, vv[3] - lse);
    float4 o1 = make_float4(vv[4] - lse, vv[5] - lse, vv[6] - lse, vv[7] - lse);
    *(float4*)&out[(size_t)wid * OUT_F + fl * 8]     = o0;
    *(float4*)&out[(size_t)wid * OUT_F + fl * 8 + 4] = o1;
  }
}

extern "C" void kernel_launch(void* const* d_in, const int* in_sizes, int n_in,
                              void* d_out, int out_size, void* d_ws, size_t ws_size,
                              hipStream_t stream) {
  const float* x   = (const float*)d_in[0];
  const int* ei    = (const int*)d_in[1];
  const float* W1  = (const float*)d_in[2];
  const float* as1 = (const float*)d_in[3];
  const float* ad1 = (const float*)d_in[4];
  const float* b1  = (const float*)d_in[5];
  const float* W2  = (const float*)d_in[6];
  const float* as2 = (const float*)d_in[7];
  const float* ad2 = (const float*)d_in[8];
  const float* b2  = (const float*)d_in[9];
  float* out = (float*)d_out;

  float* ws = (float*)d_ws;
  float* a_s1   = ws;  ws += (size_t)N_NODES * HEADS1;
  float* a_d1   = ws;  ws += (size_t)N_NODES * HEADS1;
  float* a_s2   = ws;  ws += (size_t)N_NODES;
  float* a_d2   = ws;  ws += (size_t)N_NODES;
  unsigned short* h1bf   = (unsigned short*)ws;  ws += (size_t)N_NODES * HID / 2;
  unsigned short* out1bf = (unsigned short*)ws;  ws += (size_t)N_NODES * HID / 2;
  unsigned short* h2bf   = (unsigned short*)ws;  ws += (size_t)N_NODES * OUT_F / 2;
  unsigned short* W1t = (unsigned short*)ws;  ws += (IN_F * HID) / 2;
  unsigned short* W2t = (unsigned short*)ws;  ws += (HID * OUT_F) / 2;
  int* deg      = (int*)ws;  ws += (N_NODES + 1);
  int* rowptr   = (int*)ws;  ws += (N_NODES + 1);
  int* cursor   = (int*)ws;  ws += N_NODES;
  int* csr_src  = (int*)ws;  ws += ET;
  int* exq      = (int*)ws;  ws += N_NODES;
  int* bsum     = (int*)ws;  ws += NBLK;
  int* boff     = (int*)ws;  ws += NBLK;

  // ---- weight transpose+cast (tiny; independent) ----
  wt_kernel<<<dim3((IN_F * HID + 255) / 256), dim3(256), 0, stream>>>(W1, W1t, IN_F, HID);
  wt_kernel<<<dim3((HID * OUT_F + 255) / 256), dim3(256), 0, stream>>>(W2, W2t, HID, OUT_F);

  // ---- CSR build (dst-range partitioned) ----
  hipMemsetAsync(deg, 0, sizeof(int) * (N_NODES + 1), stream);
  deg_part_kernel<<<dim3(NRANGE * BPG), dim3(256), 0, stream>>>(ei, deg);
  scan1_kernel<<<dim3(NBLK), dim3(256), 0, stream>>>(deg, exq, bsum);
  scan2_kernel<<<dim3(1), dim3(256), 0, stream>>>(bsum, boff);
  scan3_kernel<<<dim3(NBLK), dim3(256), 0, stream>>>(exq, boff, rowptr, cursor);
  scatter_part_kernel<<<dim3(NRANGE * BPG), dim3(256), 0, stream>>>(ei, cursor, csr_src);

  // ---- layer 1 ----
  gemm1_mfma_kernel<<<dim3(((N_NODES + 63) / 64) * 2), dim3(256), 0, stream>>>(x, W1t, as1, ad1, h1bf, a_s1, a_d1);
  agg1_csr_kernel<<<dim3((N_NODES + 3) / 4), dim3(256), 0, stream>>>(rowptr, csr_src, a_s1, a_d1, h1bf, b1, out1bf);

  // ---- layer 2 ----
  gemm2_mfma_kernel<<<dim3((N_NODES + 63) / 64), dim3(256), 0, stream>>>(out1bf, W2t, as2, ad2, h2bf, a_s2, a_d2);
  agg2_csr_kernel<<<dim3((N_NODES + 3) / 4), dim3(256), 0, stream>>>(rowptr, csr_src, a_s2, a_d2, h2bf, b2, out);
}

// Round 11
// 309.732 us; speedup vs baseline: 1.1176x; 1.0071x over previous
//
#include <hip/hip_runtime.h>
#include <math.h>

#define N_NODES 50000
#define E_EDGES 800000
#define ET (E_EDGES + N_NODES)   // edges + self loops
#define IN_F 256
#define HID 128
#define HEADS1 8
#define C1 16
#define OUT_F 64
#define NEG_SLOPE 0.2f
#define NBLK ((N_NODES + 255) / 256)   // 196 scan blocks
#define NRANGE 8
#define RSPAN ((N_NODES + NRANGE - 1) / NRANGE)   // 6250
#define BPG 256                                    // blocks per range-group

typedef __attribute__((ext_vector_type(8))) short short8;
typedef __attribute__((ext_vector_type(4))) float float4v;

__device__ __forceinline__ float lrelu(float v) { return v > 0.f ? v : NEG_SLOPE * v; }

__device__ __forceinline__ unsigned short f2bf(float f) {
  union { float f; unsigned u; } v; v.f = f;
  unsigned r = v.u + 0x7FFF + ((v.u >> 16) & 1);   // RNE
  return (unsigned short)(r >> 16);
}
__device__ __forceinline__ float bf2f(unsigned short u) {
  union { unsigned u; float f; } v; v.u = ((unsigned)u) << 16; return v.f;
}

// ---- W transpose+cast: Wt[n][k] bf16 from W[k][n] fp32 ----
__global__ __launch_bounds__(256) void wt_kernel(const float* __restrict__ W,
                                                 unsigned short* __restrict__ Wt,
                                                 int K, int Nc) {
  int i = blockIdx.x * 256 + threadIdx.x;
  if (i >= K * Nc) return;
  int n = i / K, k = i - n * K;
  Wt[i] = f2bf(W[k * Nc + n]);
}

// ---------------- GEMM1 (MFMA) + fused att1 epilogue, N-split 2x ----------------
// A-loads HOISTED into a 64-VGPR array: 16 independent loads in flight per wave
// (round-10 asm showed VGPR=40 -> serialized load chain -> latency-bound).
__global__ __launch_bounds__(256, 4) void gemm1_mfma_kernel(const float* __restrict__ x,
                                                            const unsigned short* __restrict__ W1t,
                                                            const float* __restrict__ att_src,
                                                            const float* __restrict__ att_dst,
                                                            unsigned short* __restrict__ h1bf,
                                                            float* __restrict__ a_s,
                                                            float* __restrict__ a_d) {
  const int ch = blockIdx.x & 1;                  // col half
  const int rb = blockIdx.x >> 1;                 // 64-row block
  const int wave = rb * 4 + (threadIdx.x >> 6);
  const int lane = threadIdx.x & 63;
  const int m0 = wave * 16;
  if (m0 >= N_NODES) return;
  const int lm = lane & 15;
  const int quad = lane >> 4;
  const int mrow = m0 + lm;
  const bool valid = mrow < N_NODES;
  const float* arow = x + (size_t)mrow * IN_F;
  const int c0 = ch * 64;                         // col base

  // ---- hoisted A loads: 8 k-chunks x 2 float4 (all independent) ----
  float4 af[8][2];
  if (valid) {
#pragma unroll
    for (int kk = 0; kk < 8; ++kk) {
      af[kk][0] = *(const float4*)(arow + kk * 32 + quad * 8);
      af[kk][1] = *(const float4*)(arow + kk * 32 + quad * 8 + 4);
    }
  } else {
#pragma unroll
    for (int kk = 0; kk < 8; ++kk) {
      af[kk][0] = make_float4(0.f, 0.f, 0.f, 0.f);
      af[kk][1] = af[kk][0];
    }
  }

  float4v acc[4];
#pragma unroll
  for (int nt = 0; nt < 4; ++nt) acc[nt] = (float4v){0.f, 0.f, 0.f, 0.f};

#pragma unroll
  for (int kk = 0; kk < 8; ++kk) {
    short8 a;
    a[0] = f2bf(af[kk][0].x); a[1] = f2bf(af[kk][0].y);
    a[2] = f2bf(af[kk][0].z); a[3] = f2bf(af[kk][0].w);
    a[4] = f2bf(af[kk][1].x); a[5] = f2bf(af[kk][1].y);
    a[6] = f2bf(af[kk][1].z); a[7] = f2bf(af[kk][1].w);
#pragma unroll
    for (int nt = 0; nt < 4; ++nt) {
      short8 b = *(const short8*)&W1t[(size_t)(c0 + nt * 16 + lm) * IN_F + kk * 32 + quad * 8];
      acc[nt] = __builtin_amdgcn_mfma_f32_16x16x32_bf16(a, b, acc[nt], 0, 0, 0);
    }
  }

#pragma unroll
  for (int nt = 0; nt < 4; ++nt) {
#pragma unroll
    for (int r = 0; r < 4; ++r) {
      int row = m0 + quad * 4 + r;
      if (row < N_NODES) h1bf[(size_t)row * HID + c0 + nt * 16 + lm] = f2bf(acc[nt][r]);
    }
  }

  // ---- fused att1: this wave owns heads ch*4 + nt (complete 16-col groups) ----
  float asv[4], adv[4];
#pragma unroll
  for (int nt = 0; nt < 4; ++nt) {
    asv[nt] = att_src[c0 + nt * 16 + lm];
    adv[nt] = att_dst[c0 + nt * 16 + lm];
  }
#pragma unroll
  for (int r = 0; r < 4; ++r) {
    int row = m0 + quad * 4 + r;
    float s[4], d[4];
#pragma unroll
    for (int nt = 0; nt < 4; ++nt) { s[nt] = acc[nt][r] * asv[nt]; d[nt] = acc[nt][r] * adv[nt]; }
#pragma unroll
    for (int m = 1; m < 16; m <<= 1) {
#pragma unroll
      for (int nt = 0; nt < 4; ++nt) { s[nt] += __shfl_xor(s[nt], m); d[nt] += __shfl_xor(d[nt], m); }
    }
    if (lm == 0 && row < N_NODES) {
#pragma unroll
      for (int nt = 0; nt < 4; ++nt) {
        a_s[(size_t)row * HEADS1 + ch * 4 + nt] = s[nt];
        a_d[(size_t)row * HEADS1 + ch * 4 + nt] = d[nt];
      }
    }
  }
}

// ---------------- GEMM2 (MFMA) + fused att2 epilogue, hoisted A ----------------
__global__ __launch_bounds__(256, 4) void gemm2_mfma_kernel(const unsigned short* __restrict__ in,
                                                            const unsigned short* __restrict__ W2t,
                                                            const float* __restrict__ att_src,
                                                            const float* __restrict__ att_dst,
                                                            unsigned short* __restrict__ h2bf,
                                                            float* __restrict__ a_s,
                                                            float* __restrict__ a_d) {
  const int wave = blockIdx.x * 4 + (threadIdx.x >> 6);
  const int lane = threadIdx.x & 63;
  const int m0 = wave * 16;
  if (m0 >= N_NODES) return;
  const int lm = lane & 15;
  const int quad = lane >> 4;
  const int mrow = m0 + lm;
  const bool valid = mrow < N_NODES;
  const unsigned short* arow = in + (size_t)mrow * HID;

  // hoisted A loads: 4 independent short8 loads
  short8 af[4];
  if (valid) {
#pragma unroll
    for (int kk = 0; kk < 4; ++kk) af[kk] = *(const short8*)(arow + kk * 32 + quad * 8);
  } else {
#pragma unroll
    for (int kk = 0; kk < 4; ++kk) af[kk] = (short8){0, 0, 0, 0, 0, 0, 0, 0};
  }

  float4v acc[4];
#pragma unroll
  for (int nt = 0; nt < 4; ++nt) acc[nt] = (float4v){0.f, 0.f, 0.f, 0.f};

#pragma unroll
  for (int kk = 0; kk < 4; ++kk) {
#pragma unroll
    for (int nt = 0; nt < 4; ++nt) {
      short8 b = *(const short8*)&W2t[(size_t)(nt * 16 + lm) * HID + kk * 32 + quad * 8];
      acc[nt] = __builtin_amdgcn_mfma_f32_16x16x32_bf16(af[kk], b, acc[nt], 0, 0, 0);
    }
  }

#pragma unroll
  for (int nt = 0; nt < 4; ++nt) {
#pragma unroll
    for (int r = 0; r < 4; ++r) {
      int row = m0 + quad * 4 + r;
      if (row < N_NODES) h2bf[(size_t)row * OUT_F + nt * 16 + lm] = f2bf(acc[nt][r]);
    }
  }

  // ---- fused att2: single head over 64 cols ----
  float as0 = att_src[lm], as1v = att_src[16 + lm], as2v = att_src[32 + lm], as3 = att_src[48 + lm];
  float ad0 = att_dst[lm], ad1v = att_dst[16 + lm], ad2v = att_dst[32 + lm], ad3 = att_dst[48 + lm];
#pragma unroll
  for (int r = 0; r < 4; ++r) {
    int row = m0 + quad * 4 + r;
    float s = acc[0][r] * as0 + acc[1][r] * as1v + acc[2][r] * as2v + acc[3][r] * as3;
    float d = acc[0][r] * ad0 + acc[1][r] * ad1v + acc[2][r] * ad2v + acc[3][r] * ad3;
#pragma unroll
    for (int m = 1; m < 16; m <<= 1) { s += __shfl_xor(s, m); d += __shfl_xor(d, m); }
    if (lm == 0 && row < N_NODES) { a_s[row] = s; a_d[row] = d; }
  }
}

// ---------------- CSR construction (dst-range partitioned for L2 locality) ------
__global__ __launch_bounds__(256) void deg_part_kernel(const int* __restrict__ ei,
                                                       int* __restrict__ deg) {
  const int g = blockIdx.x & (NRANGE - 1);
  const int tg = (blockIdx.x >> 3) * 256 + threadIdx.x;   // thread idx in group
  const int lo = g * RSPAN, hi = lo + RSPAN;
  for (int e = tg; e < ET; e += BPG * 256) {
    int d = (e < E_EDGES) ? ei[E_EDGES + e] : (e - E_EDGES);
    if (d >= lo && d < hi) atomicAdd(&deg[d], 1);
  }
}

__global__ __launch_bounds__(256) void scatter_part_kernel(const int* __restrict__ ei,
                                                           int* __restrict__ cursor,
                                                           int* __restrict__ csr_src) {
  const int g = blockIdx.x & (NRANGE - 1);
  const int tg = (blockIdx.x >> 3) * 256 + threadIdx.x;
  const int lo = g * RSPAN, hi = lo + RSPAN;
  for (int e = tg; e < ET; e += BPG * 256) {
    int d = (e < E_EDGES) ? ei[E_EDGES + e] : (e - E_EDGES);
    if (d >= lo && d < hi) {
      int s = (e < E_EDGES) ? ei[e] : d;
      int pos = atomicAdd(&cursor[d], 1);
      csr_src[pos] = s;
    }
  }
}

__global__ __launch_bounds__(256) void scan1_kernel(const int* __restrict__ deg,
                                                    int* __restrict__ exq,
                                                    int* __restrict__ bsum) {
  __shared__ int sh[256];
  const int t = threadIdx.x;
  const int idx = blockIdx.x * 256 + t;
  int v = (idx < N_NODES) ? deg[idx] : 0;
  sh[t] = v;
  __syncthreads();
  for (int off = 1; off < 256; off <<= 1) {
    int u = (t >= off) ? sh[t - off] : 0;
    __syncthreads();
    sh[t] += u;
    __syncthreads();
  }
  if (idx < N_NODES) exq[idx] = sh[t] - v;
  if (t == 255) bsum[blockIdx.x] = sh[t];
}

__global__ __launch_bounds__(256) void scan2_kernel(const int* __restrict__ bsum,
                                                    int* __restrict__ boff) {
  __shared__ int sh[256];
  const int t = threadIdx.x;
  int v = (t < NBLK) ? bsum[t] : 0;
  sh[t] = v;
  __syncthreads();
  for (int off = 1; off < 256; off <<= 1) {
    int u = (t >= off) ? sh[t - off] : 0;
    __syncthreads();
    sh[t] += u;
    __syncthreads();
  }
  if (t < NBLK) boff[t] = sh[t] - v;
}

__global__ __launch_bounds__(256) void scan3_kernel(const int* __restrict__ exq,
                                                    const int* __restrict__ boff,
                                                    int* __restrict__ rowptr,
                                                    int* __restrict__ cursor) {
  const int idx = blockIdx.x * 256 + threadIdx.x;
  if (idx < N_NODES) {
    int r = exq[idx] + boff[blockIdx.x];
    rowptr[idx] = r;
    cursor[idx] = r;
  }
  if (idx == 0) rowptr[N_NODES] = ET;
}

// ---------------- agg1: wave/dst; 16-lane×16B row gathers (4 edges/instr) -------
__global__ __launch_bounds__(256) void agg1_csr_kernel(const int* __restrict__ rowptr,
                                                       const int* __restrict__ csr_src,
                                                       const float* __restrict__ a_s,
                                                       const float* __restrict__ a_d,
                                                       const unsigned short* __restrict__ h1bf,
                                                       const float* __restrict__ b1,
                                                       unsigned short* __restrict__ out1bf) {
  int wid = (blockIdx.x * 256 + threadIdx.x) >> 6;
  int lane = threadIdx.x & 63;
  if (wid >= N_NODES) return;
  const int fl = lane & 15;
  const int g  = lane >> 4;
  const int myh = fl >> 1;
  const float adn = a_d[(size_t)wid * HEADS1 + myh];
  const int start = rowptr[wid], end = rowptr[wid + 1];
  float acc[8];
#pragma unroll
  for (int k = 0; k < 8; ++k) acc[k] = 0.f;
  float wsum = 0.f;

  for (int i = start; i < end; i += 8) {
    int e0 = i + g, e1 = i + 4 + g;
    bool v0 = e0 < end, v1 = e1 < end;
    int s0 = csr_src[v0 ? e0 : start];
    int s1 = csr_src[v1 ? e1 : start];
    float l0 = a_s[(size_t)s0 * HEADS1 + myh];
    float l1 = a_s[(size_t)s1 * HEADS1 + myh];
    short8 r0 = *(const short8*)&h1bf[(size_t)s0 * HID + fl * 8];
    short8 r1 = *(const short8*)&h1bf[(size_t)s1 * HID + fl * 8];
    float w0 = v0 ? __expf(lrelu(l0 + adn)) : 0.f;
    float w1 = v1 ? __expf(lrelu(l1 + adn)) : 0.f;
#pragma unroll
    for (int k = 0; k < 8; ++k)
      acc[k] += w0 * bf2f((unsigned short)r0[k]) + w1 * bf2f((unsigned short)r1[k]);
    wsum += w0 + w1;
  }

#pragma unroll
  for (int k = 0; k < 8; ++k) {
    acc[k] += __shfl_xor(acc[k], 16);
    acc[k] += __shfl_xor(acc[k], 32);
  }
  wsum += __shfl_xor(wsum, 16);
  wsum += __shfl_xor(wsum, 32);

  if (g == 0) {
    float inv = 1.f / (wsum + 1e-16f);
    float4 blo = *(const float4*)&b1[fl * 8];
    float4 bhi = *(const float4*)&b1[fl * 8 + 4];
    float vv[8];
    vv[0] = acc[0] * inv + blo.x; vv[1] = acc[1] * inv + blo.y;
    vv[2] = acc[2] * inv + blo.z; vv[3] = acc[3] * inv + blo.w;
    vv[4] = acc[4] * inv + bhi.x; vv[5] = acc[5] * inv + bhi.y;
    vv[6] = acc[6] * inv + bhi.z; vv[7] = acc[7] * inv + bhi.w;
    short8 o;
#pragma unroll
    for (int k = 0; k < 8; ++k) {
      float e = vv[k] > 0.f ? vv[k] : expm1f(vv[k]);
      o[k] = (short)f2bf(e);
    }
    *(short8*)&out1bf[(size_t)wid * HID + fl * 8] = o;
  }
}

// ---------------- agg2: wave/dst; 8-lane×16B row gathers (8 edges/instr) --------
__global__ __launch_bounds__(256) void agg2_csr_kernel(const int* __restrict__ rowptr,
                                                       const int* __restrict__ csr_src,
                                                       const float* __restrict__ a_s,
                                                       const float* __restrict__ a_d,
                                                       const unsigned short* __restrict__ h2bf,
                                                       const float* __restrict__ b2,
                                                       float* __restrict__ out) {
  int wid = (blockIdx.x * 256 + threadIdx.x) >> 6;
  int lane = threadIdx.x & 63;
  if (wid >= N_NODES) return;
  const int fl = lane & 7;       // owns feats [8*fl, 8*fl+8)
  const int g  = lane >> 3;      // edge group 0..7
  const float adn = a_d[wid];
  const int start = rowptr[wid], end = rowptr[wid + 1];
  float acc[8];
#pragma unroll
  for (int k = 0; k < 8; ++k) acc[k] = 0.f;
  float wsum = 0.f;

  for (int i = start; i < end; i += 16) {
    int e0 = i + g, e1 = i + 8 + g;
    bool v0 = e0 < end, v1 = e1 < end;
    int s0 = csr_src[v0 ? e0 : start];
    int s1 = csr_src[v1 ? e1 : start];
    float l0 = a_s[s0];
    float l1 = a_s[s1];
    short8 r0 = *(const short8*)&h2bf[(size_t)s0 * OUT_F + fl * 8];
    short8 r1 = *(const short8*)&h2bf[(size_t)s1 * OUT_F + fl * 8];
    float w0 = v0 ? __expf(lrelu(l0 + adn)) : 0.f;
    float w1 = v1 ? __expf(lrelu(l1 + adn)) : 0.f;
#pragma unroll
    for (int k = 0; k < 8; ++k)
      acc[k] += w0 * bf2f((unsigned short)r0[k]) + w1 * bf2f((unsigned short)r1[k]);
    wsum += w0 + w1;
  }

#pragma unroll
  for (int k = 0; k < 8; ++k) {
    acc[k] += __shfl_xor(acc[k], 8);
    acc[k] += __shfl_xor(acc[k], 16);
    acc[k] += __shfl_xor(acc[k], 32);
  }
  wsum += __shfl_xor(wsum, 8);
  wsum += __shfl_xor(wsum, 16);
  wsum += __shfl_xor(wsum, 32);

  float inv = 1.f / (wsum + 1e-16f);
  float4 blo = *(const float4*)&b2[fl * 8];
  float4 bhi = *(const float4*)&b2[fl * 8 + 4];
  float vv[8];
  vv[0] = acc[0] * inv + blo.x; vv[1] = acc[1] * inv + blo.y;
  vv[2] = acc[2] * inv + blo.z; vv[3] = acc[3] * inv + blo.w;
  vv[4] = acc[4] * inv + bhi.x; vv[5] = acc[5] * inv + bhi.y;
  vv[6] = acc[6] * inv + bhi.z; vv[7] = acc[7] * inv + bhi.w;
  float m = vv[0];
#pragma unroll
  for (int k = 1; k < 8; ++k) m = fmaxf(m, vv[k]);
#pragma unroll
  for (int msk = 1; msk < 8; msk <<= 1) m = fmaxf(m, __shfl_xor(m, msk));
  float sm = 0.f;
#pragma unroll
  for (int k = 0; k < 8; ++k) sm += __expf(vv[k] - m);
#pragma unroll
  for (int msk = 1; msk < 8; msk <<= 1) sm += __shfl_xor(sm, msk);
  float lse = m + __logf(sm);
  if (g == 0) {
    float4 o0 = make_float4(vv[0] - lse, vv[1] - lse, vv[2] - lse, vv[3] - lse);
    float4 o1 = make_float4(vv[4] - lse, vv[5] - lse, vv[6] - lse, vv[7] - lse);
    *(float4*)&out[(size_t)wid * OUT_F + fl * 8]     = o0;
    *(float4*)&out[(size_t)wid * OUT_F + fl * 8 + 4] = o1;
  }
}

extern "C" void kernel_launch(void* const* d_in, const int* in_sizes, int n_in,
                              void* d_out, int out_size, void* d_ws, size_t ws_size,
                              hipStream_t stream) {
  const float* x   = (const float*)d_in[0];
  const int* ei    = (const int*)d_in[1];
  const float* W1  = (const float*)d_in[2];
  const float* as1 = (const float*)d_in[3];
  const float* ad1 = (const float*)d_in[4];
  const float* b1  = (const float*)d_in[5];
  const float* W2  = (const float*)d_in[6];
  const float* as2 = (const float*)d_in[7];
  const float* ad2 = (const float*)d_in[8];
  const float* b2  = (const float*)d_in[9];
  float* out = (float*)d_out;

  float* ws = (float*)d_ws;
  float* a_s1   = ws;  ws += (size_t)N_NODES * HEADS1;
  float* a_d1   = ws;  ws += (size_t)N_NODES * HEADS1;
  float* a_s2   = ws;  ws += (size_t)N_NODES;
  float* a_d2   = ws;  ws += (size_t)N_NODES;
  unsigned short* h1bf   = (unsigned short*)ws;  ws += (size_t)N_NODES * HID / 2;
  unsigned short* out1bf = (unsigned short*)ws;  ws += (size_t)N_NODES * HID / 2;
  unsigned short* h2bf   = (unsigned short*)ws;  ws += (size_t)N_NODES * OUT_F / 2;
  unsigned short* W1t = (unsigned short*)ws;  ws += (IN_F * HID) / 2;
  unsigned short* W2t = (unsigned short*)ws;  ws += (HID * OUT_F) / 2;
  int* deg      = (int*)ws;  ws += (N_NODES + 1);
  int* rowptr   = (int*)ws;  ws += (N_NODES + 1);
  int* cursor   = (int*)ws;  ws += N_NODES;
  int* csr_src  = (int*)ws;  ws += ET;
  int* exq      = (int*)ws;  ws += N_NODES;
  int* bsum     = (int*)ws;  ws += NBLK;
  int* boff     = (int*)ws;  ws += NBLK;

  // ---- weight transpose+cast (tiny; independent) ----
  wt_kernel<<<dim3((IN_F * HID + 255) / 256), dim3(256), 0, stream>>>(W1, W1t, IN_F, HID);
  wt_kernel<<<dim3((HID * OUT_F + 255) / 256), dim3(256), 0, stream>>>(W2, W2t, HID, OUT_F);

  // ---- CSR build (dst-range partitioned) ----
  hipMemsetAsync(deg, 0, sizeof(int) * (N_NODES + 1), stream);
  deg_part_kernel<<<dim3(NRANGE * BPG), dim3(256), 0, stream>>>(ei, deg);
  scan1_kernel<<<dim3(NBLK), dim3(256), 0, stream>>>(deg, exq, bsum);
  scan2_kernel<<<dim3(1), dim3(256), 0, stream>>>(bsum, boff);
  scan3_kernel<<<dim3(NBLK), dim3(256), 0, stream>>>(exq, boff, rowptr, cursor);
  scatter_part_kernel<<<dim3(NRANGE * BPG), dim3(256), 0, stream>>>(ei, cursor, csr_src);

  // ---- layer 1 ----
  gemm1_mfma_kernel<<<dim3(((N_NODES + 63) / 64) * 2), dim3(256), 0, stream>>>(x, W1t, as1, ad1, h1bf, a_s1, a_d1);
  agg1_csr_kernel<<<dim3((N_NODES + 3) / 4), dim3(256), 0, stream>>>(rowptr, csr_src, a_s1, a_d1, h1bf, b1, out1bf);

  // ---- layer 2 ----
  gemm2_mfma_kernel<<<dim3((N_NODES + 63) / 64), dim3(256), 0, stream>>>(out1bf, W2t, as2, ad2, h2bf, a_s2, a_d2);
  agg2_csr_kernel<<<dim3((N_NODES + 3) / 4), dim3(256), 0, stream>>>(rowptr, csr_src, a_s2, a_d2, h2bf, b2, out);
}

// Round 12
// 299.735 us; speedup vs baseline: 1.1549x; 1.0334x over previous
//
#include <hip/hip_runtime.h>
#include <math.h>

#define N_NODES 50000
#define E_EDGES 800000
#define ET (E_EDGES + N_NODES)   // edges + self loops
#define IN_F 256
#define HID 128
#define HEADS1 8
#define C1 16
#define OUT_F 64
#define NEG_SLOPE 0.2f
#define NBLK ((N_NODES + 255) / 256)   // 196 scan blocks
#define NRANGE 8
#define RSPAN ((N_NODES + NRANGE - 1) / NRANGE)   // 6250
#define BPG 256                                    // blocks per range-group

typedef __attribute__((ext_vector_type(8))) short short8;
typedef __attribute__((ext_vector_type(4))) float float4v;

__device__ __forceinline__ float lrelu(float v) { return v > 0.f ? v : NEG_SLOPE * v; }

__device__ __forceinline__ unsigned short f2bf(float f) {
  union { float f; unsigned u; } v; v.f = f;
  unsigned r = v.u + 0x7FFF + ((v.u >> 16) & 1);   // RNE
  return (unsigned short)(r >> 16);
}
__device__ __forceinline__ float bf2f(unsigned short u) {
  union { unsigned u; float f; } v; v.u = ((unsigned)u) << 16; return v.f;
}

// async global->LDS, 16B per lane; lds dest must be WAVE-UNIFORM base (lane i -> base + 16*i)
__device__ __forceinline__ void stage16(const void* g, void* l) {
  __builtin_amdgcn_global_load_lds((const __attribute__((address_space(1))) void*)g,
                                   (__attribute__((address_space(3))) void*)l, 16, 0, 0);
}
#define WAIT_VM0()   asm volatile("s_waitcnt vmcnt(0)" ::: "memory")
#define WAIT_LGKM0() asm volatile("s_waitcnt lgkmcnt(0)" ::: "memory")

// ---- W transpose+cast: Wt[n][k] bf16 from W[k][n] fp32 ----
__global__ __launch_bounds__(256) void wt_kernel(const float* __restrict__ W,
                                                 unsigned short* __restrict__ Wt,
                                                 int K, int Nc) {
  int i = blockIdx.x * 256 + threadIdx.x;
  if (i >= K * Nc) return;
  int n = i / K, k = i - n * K;
  Wt[i] = f2bf(W[k * Nc + n]);
}

// ---------------- GEMM1 (MFMA) + fused att1; A staged via global_load_lds -------
// Wave owns 16 rows x 128 cols. Each wave stages ITS OWN rows into a private 2KB
// LDS slice -> no __syncthreads anywhere; only per-wave vmcnt waits.
// N_NODES % 16 == 0, so all active waves have 16 valid rows.
__global__ __launch_bounds__(256) void gemm1_mfma_kernel(const float* __restrict__ x,
                                                         const unsigned short* __restrict__ W1t,
                                                         const float* __restrict__ att_src,
                                                         const float* __restrict__ att_dst,
                                                         unsigned short* __restrict__ h1bf,
                                                         float* __restrict__ a_s,
                                                         float* __restrict__ a_d) {
  __shared__ float As[4 * 512];                   // 4 waves x (16 rows x 32 floats) = 8KB
  const int wv = threadIdx.x >> 6;
  const int wave = blockIdx.x * 4 + wv;
  const int lane = threadIdx.x & 63;
  const int m0 = wave * 16;
  if (m0 >= N_NODES) return;                      // whole-wave exit; no barriers in kernel
  const int lm = lane & 15;
  const int quad = lane >> 4;
  float* myA = &As[wv * 512];

  // staging source addresses (per-lane): instr j covers rows m0+j*8+(lane>>3), chunk (lane&7)*4 floats
  const float* g0 = x + (size_t)(m0 + (lane >> 3)) * IN_F + (lane & 7) * 4;
  const float* g1 = x + (size_t)(m0 + 8 + (lane >> 3)) * IN_F + (lane & 7) * 4;

  float4v acc[8];
#pragma unroll
  for (int nt = 0; nt < 8; ++nt) acc[nt] = (float4v){0.f, 0.f, 0.f, 0.f};

#pragma unroll
  for (int kk = 0; kk < 8; ++kk) {                // K = 8 x 32
    WAIT_LGKM0();                                 // prior ds_reads retired before LDS overwrite
    stage16(g0 + kk * 32, myA);                   // rows 0..7  of this wave's tile
    stage16(g1 + kk * 32, myA + 256);             // rows 8..15
    short8 bfr[8];
#pragma unroll
    for (int nt = 0; nt < 8; ++nt)
      bfr[nt] = *(const short8*)&W1t[(size_t)(nt * 16 + lm) * IN_F + kk * 32 + quad * 8];
    WAIT_VM0();                                   // stage + B loads complete
    float4 a0 = *(const float4*)&myA[lm * 32 + quad * 8];
    float4 a1 = *(const float4*)&myA[lm * 32 + quad * 8 + 4];
    short8 a;
    a[0] = f2bf(a0.x); a[1] = f2bf(a0.y); a[2] = f2bf(a0.z); a[3] = f2bf(a0.w);
    a[4] = f2bf(a1.x); a[5] = f2bf(a1.y); a[6] = f2bf(a1.z); a[7] = f2bf(a1.w);
#pragma unroll
    for (int nt = 0; nt < 8; ++nt)
      acc[nt] = __builtin_amdgcn_mfma_f32_16x16x32_bf16(a, bfr[nt], acc[nt], 0, 0, 0);
  }

#pragma unroll
  for (int nt = 0; nt < 8; ++nt) {
#pragma unroll
    for (int r = 0; r < 4; ++r) {
      int row = m0 + quad * 4 + r;
      h1bf[(size_t)row * HID + nt * 16 + lm] = f2bf(acc[nt][r]);
    }
  }

  // ---- fused att1: per-head dot over cols; reduce over lm (16 lanes) ----
  float asv[8], adv[8];
#pragma unroll
  for (int nt = 0; nt < 8; ++nt) { asv[nt] = att_src[nt * 16 + lm]; adv[nt] = att_dst[nt * 16 + lm]; }
#pragma unroll
  for (int r = 0; r < 4; ++r) {
    int row = m0 + quad * 4 + r;
    float s[8], d[8];
#pragma unroll
    for (int nt = 0; nt < 8; ++nt) { s[nt] = acc[nt][r] * asv[nt]; d[nt] = acc[nt][r] * adv[nt]; }
#pragma unroll
    for (int m = 1; m < 16; m <<= 1) {
#pragma unroll
      for (int nt = 0; nt < 8; ++nt) { s[nt] += __shfl_xor(s[nt], m); d[nt] += __shfl_xor(d[nt], m); }
    }
    if (lm == 0) {
#pragma unroll
      for (int nt = 0; nt < 8; ++nt) {
        a_s[(size_t)row * HEADS1 + nt] = s[nt];
        a_d[(size_t)row * HEADS1 + nt] = d[nt];
      }
    }
  }
}

// ---------------- GEMM2 (MFMA) + fused att2; A staged via global_load_lds -------
__global__ __launch_bounds__(256) void gemm2_mfma_kernel(const unsigned short* __restrict__ in,
                                                         const unsigned short* __restrict__ W2t,
                                                         const float* __restrict__ att_src,
                                                         const float* __restrict__ att_dst,
                                                         unsigned short* __restrict__ h2bf,
                                                         float* __restrict__ a_s,
                                                         float* __restrict__ a_d) {
  __shared__ unsigned short Bs[4 * 512];          // 4 waves x (16 rows x 32 bf16) = 4KB
  const int wv = threadIdx.x >> 6;
  const int wave = blockIdx.x * 4 + wv;
  const int lane = threadIdx.x & 63;
  const int m0 = wave * 16;
  if (m0 >= N_NODES) return;
  const int lm = lane & 15;
  const int quad = lane >> 4;
  unsigned short* myA = &Bs[wv * 512];

  // one stage instr covers all 16 rows: row m0+(lane>>2), chunk (lane&3)*8 ushorts
  const unsigned short* gsrc = in + (size_t)(m0 + (lane >> 2)) * HID + (lane & 3) * 8;

  float4v acc[4];
#pragma unroll
  for (int nt = 0; nt < 4; ++nt) acc[nt] = (float4v){0.f, 0.f, 0.f, 0.f};

#pragma unroll
  for (int kk = 0; kk < 4; ++kk) {                // K = 4 x 32
    WAIT_LGKM0();
    stage16(gsrc + kk * 32, myA);
    short8 bfr[4];
#pragma unroll
    for (int nt = 0; nt < 4; ++nt)
      bfr[nt] = *(const short8*)&W2t[(size_t)(nt * 16 + lm) * HID + kk * 32 + quad * 8];
    WAIT_VM0();
    short8 a = *(const short8*)&myA[lm * 32 + quad * 8];
#pragma unroll
    for (int nt = 0; nt < 4; ++nt)
      acc[nt] = __builtin_amdgcn_mfma_f32_16x16x32_bf16(a, bfr[nt], acc[nt], 0, 0, 0);
  }

#pragma unroll
  for (int nt = 0; nt < 4; ++nt) {
#pragma unroll
    for (int r = 0; r < 4; ++r) {
      int row = m0 + quad * 4 + r;
      h2bf[(size_t)row * OUT_F + nt * 16 + lm] = f2bf(acc[nt][r]);
    }
  }

  // ---- fused att2: single head over 64 cols ----
  float as0 = att_src[lm], as1v = att_src[16 + lm], as2v = att_src[32 + lm], as3 = att_src[48 + lm];
  float ad0 = att_dst[lm], ad1v = att_dst[16 + lm], ad2v = att_dst[32 + lm], ad3 = att_dst[48 + lm];
#pragma unroll
  for (int r = 0; r < 4; ++r) {
    int row = m0 + quad * 4 + r;
    float s = acc[0][r] * as0 + acc[1][r] * as1v + acc[2][r] * as2v + acc[3][r] * as3;
    float d = acc[0][r] * ad0 + acc[1][r] * ad1v + acc[2][r] * ad2v + acc[3][r] * ad3;
#pragma unroll
    for (int m = 1; m < 16; m <<= 1) { s += __shfl_xor(s, m); d += __shfl_xor(d, m); }
    if (lm == 0) { a_s[row] = s; a_d[row] = d; }
  }
}

// ---------------- CSR construction (dst-range partitioned for L2 locality) ------
__global__ __launch_bounds__(256) void deg_part_kernel(const int* __restrict__ ei,
                                                       int* __restrict__ deg) {
  const int g = blockIdx.x & (NRANGE - 1);
  const int tg = (blockIdx.x >> 3) * 256 + threadIdx.x;   // thread idx in group
  const int lo = g * RSPAN, hi = lo + RSPAN;
  for (int e = tg; e < ET; e += BPG * 256) {
    int d = (e < E_EDGES) ? ei[E_EDGES + e] : (e - E_EDGES);
    if (d >= lo && d < hi) atomicAdd(&deg[d], 1);
  }
}

__global__ __launch_bounds__(256) void scatter_part_kernel(const int* __restrict__ ei,
                                                           int* __restrict__ cursor,
                                                           int* __restrict__ csr_src) {
  const int g = blockIdx.x & (NRANGE - 1);
  const int tg = (blockIdx.x >> 3) * 256 + threadIdx.x;
  const int lo = g * RSPAN, hi = lo + RSPAN;
  for (int e = tg; e < ET; e += BPG * 256) {
    int d = (e < E_EDGES) ? ei[E_EDGES + e] : (e - E_EDGES);
    if (d >= lo && d < hi) {
      int s = (e < E_EDGES) ? ei[e] : d;
      int pos = atomicAdd(&cursor[d], 1);
      csr_src[pos] = s;
    }
  }
}

__global__ __launch_bounds__(256) void scan1_kernel(const int* __restrict__ deg,
                                                    int* __restrict__ exq,
                                                    int* __restrict__ bsum) {
  __shared__ int sh[256];
  const int t = threadIdx.x;
  const int idx = blockIdx.x * 256 + t;
  int v = (idx < N_NODES) ? deg[idx] : 0;
  sh[t] = v;
  __syncthreads();
  for (int off = 1; off < 256; off <<= 1) {
    int u = (t >= off) ? sh[t - off] : 0;
    __syncthreads();
    sh[t] += u;
    __syncthreads();
  }
  if (idx < N_NODES) exq[idx] = sh[t] - v;
  if (t == 255) bsum[blockIdx.x] = sh[t];
}

__global__ __launch_bounds__(256) void scan2_kernel(const int* __restrict__ bsum,
                                                    int* __restrict__ boff) {
  __shared__ int sh[256];
  const int t = threadIdx.x;
  int v = (t < NBLK) ? bsum[t] : 0;
  sh[t] = v;
  __syncthreads();
  for (int off = 1; off < 256; off <<= 1) {
    int u = (t >= off) ? sh[t - off] : 0;
    __syncthreads();
    sh[t] += u;
    __syncthreads();
  }
  if (t < NBLK) boff[t] = sh[t] - v;
}

__global__ __launch_bounds__(256) void scan3_kernel(const int* __restrict__ exq,
                                                    const int* __restrict__ boff,
                                                    int* __restrict__ rowptr,
                                                    int* __restrict__ cursor) {
  const int idx = blockIdx.x * 256 + threadIdx.x;
  if (idx < N_NODES) {
    int r = exq[idx] + boff[blockIdx.x];
    rowptr[idx] = r;
    cursor[idx] = r;
  }
  if (idx == 0) rowptr[N_NODES] = ET;
}

// ---------------- agg1: wave/dst; 16-lane×16B row gathers (4 edges/instr) -------
__global__ __launch_bounds__(256) void agg1_csr_kernel(const int* __restrict__ rowptr,
                                                       const int* __restrict__ csr_src,
                                                       const float* __restrict__ a_s,
                                                       const float* __restrict__ a_d,
                                                       const unsigned short* __restrict__ h1bf,
                                                       const float* __restrict__ b1,
                                                       unsigned short* __restrict__ out1bf) {
  int wid = (blockIdx.x * 256 + threadIdx.x) >> 6;
  int lane = threadIdx.x & 63;
  if (wid >= N_NODES) return;
  const int fl = lane & 15;
  const int g  = lane >> 4;
  const int myh = fl >> 1;
  const float adn = a_d[(size_t)wid * HEADS1 + myh];
  const int start = rowptr[wid], end = rowptr[wid + 1];
  float acc[8];
#pragma unroll
  for (int k = 0; k < 8; ++k) acc[k] = 0.f;
  float wsum = 0.f;

  for (int i = start; i < end; i += 8) {
    int e0 = i + g, e1 = i + 4 + g;
    bool v0 = e0 < end, v1 = e1 < end;
    int s0 = csr_src[v0 ? e0 : start];
    int s1 = csr_src[v1 ? e1 : start];
    float l0 = a_s[(size_t)s0 * HEADS1 + myh];
    float l1 = a_s[(size_t)s1 * HEADS1 + myh];
    short8 r0 = *(const short8*)&h1bf[(size_t)s0 * HID + fl * 8];
    short8 r1 = *(const short8*)&h1bf[(size_t)s1 * HID + fl * 8];
    float w0 = v0 ? __expf(lrelu(l0 + adn)) : 0.f;
    float w1 = v1 ? __expf(lrelu(l1 + adn)) : 0.f;
#pragma unroll
    for (int k = 0; k < 8; ++k)
      acc[k] += w0 * bf2f((unsigned short)r0[k]) + w1 * bf2f((unsigned short)r1[k]);
    wsum += w0 + w1;
  }

#pragma unroll
  for (int k = 0; k < 8; ++k) {
    acc[k] += __shfl_xor(acc[k], 16);
    acc[k] += __shfl_xor(acc[k], 32);
  }
  wsum += __shfl_xor(wsum, 16);
  wsum += __shfl_xor(wsum, 32);

  if (g == 0) {
    float inv = 1.f / (wsum + 1e-16f);
    float4 blo = *(const float4*)&b1[fl * 8];
    float4 bhi = *(const float4*)&b1[fl * 8 + 4];
    float vv[8];
    vv[0] = acc[0] * inv + blo.x; vv[1] = acc[1] * inv + blo.y;
    vv[2] = acc[2] * inv + blo.z; vv[3] = acc[3] * inv + blo.w;
    vv[4] = acc[4] * inv + bhi.x; vv[5] = acc[5] * inv + bhi.y;
    vv[6] = acc[6] * inv + bhi.z; vv[7] = acc[7] * inv + bhi.w;
    short8 o;
#pragma unroll
    for (int k = 0; k < 8; ++k) {
      float e = vv[k] > 0.f ? vv[k] : expm1f(vv[k]);
      o[k] = (short)f2bf(e);
    }
    *(short8*)&out1bf[(size_t)wid * HID + fl * 8] = o;
  }
}

// ---------------- agg2: wave/dst; 8-lane×16B row gathers (8 edges/instr) --------
__global__ __launch_bounds__(256) void agg2_csr_kernel(const int* __restrict__ rowptr,
                                                       const int* __restrict__ csr_src,
                                                       const float* __restrict__ a_s,
                                                       const float* __restrict__ a_d,
                                                       const unsigned short* __restrict__ h2bf,
                                                       const float* __restrict__ b2,
                                                       float* __restrict__ out) {
  int wid = (blockIdx.x * 256 + threadIdx.x) >> 6;
  int lane = threadIdx.x & 63;
  if (wid >= N_NODES) return;
  const int fl = lane & 7;       // owns feats [8*fl, 8*fl+8)
  const int g  = lane >> 3;      // edge group 0..7
  const float adn = a_d[wid];
  const int start = rowptr[wid], end = rowptr[wid + 1];
  float acc[8];
#pragma unroll
  for (int k = 0; k < 8; ++k) acc[k] = 0.f;
  float wsum = 0.f;

  for (int i = start; i < end; i += 16) {
    int e0 = i + g, e1 = i + 8 + g;
    bool v0 = e0 < end, v1 = e1 < end;
    int s0 = csr_src[v0 ? e0 : start];
    int s1 = csr_src[v1 ? e1 : start];
    float l0 = a_s[s0];
    float l1 = a_s[s1];
    short8 r0 = *(const short8*)&h2bf[(size_t)s0 * OUT_F + fl * 8];
    short8 r1 = *(const short8*)&h2bf[(size_t)s1 * OUT_F + fl * 8];
    float w0 = v0 ? __expf(lrelu(l0 + adn)) : 0.f;
    float w1 = v1 ? __expf(lrelu(l1 + adn)) : 0.f;
#pragma unroll
    for (int k = 0; k < 8; ++k)
      acc[k] += w0 * bf2f((unsigned short)r0[k]) + w1 * bf2f((unsigned short)r1[k]);
    wsum += w0 + w1;
  }

#pragma unroll
  for (int k = 0; k < 8; ++k) {
    acc[k] += __shfl_xor(acc[k], 8);
    acc[k] += __shfl_xor(acc[k], 16);
    acc[k] += __shfl_xor(acc[k], 32);
  }
  wsum += __shfl_xor(wsum, 8);
  wsum += __shfl_xor(wsum, 16);
  wsum += __shfl_xor(wsum, 32);

  float inv = 1.f / (wsum + 1e-16f);
  float4 blo = *(const float4*)&b2[fl * 8];
  float4 bhi = *(const float4*)&b2[fl * 8 + 4];
  float vv[8];
  vv[0] = acc[0] * inv + blo.x; vv[1] = acc[1] * inv + blo.y;
  vv[2] = acc[2] * inv + blo.z; vv[3] = acc[3] * inv + blo.w;
  vv[4] = acc[4] * inv + bhi.x; vv[5] = acc[5] * inv + bhi.y;
  vv[6] = acc[6] * inv + bhi.z; vv[7] = acc[7] * inv + bhi.w;
  float m = vv[0];
#pragma unroll
  for (int k = 1; k < 8; ++k) m = fmaxf(m, vv[k]);
#pragma unroll
  for (int msk = 1; msk < 8; msk <<= 1) m = fmaxf(m, __shfl_xor(m, msk));
  float sm = 0.f;
#pragma unroll
  for (int k = 0; k < 8; ++k) sm += __expf(vv[k] - m);
#pragma unroll
  for (int msk = 1; msk < 8; msk <<= 1) sm += __shfl_xor(sm, msk);
  float lse = m + __logf(sm);
  if (g == 0) {
    float4 o0 = make_float4(vv[0] - lse, vv[1] - lse, vv[2] - lse, vv[3] - lse);
    float4 o1 = make_float4(vv[4] - lse, vv[5] - lse, vv[6] - lse, vv[7] - lse);
    *(float4*)&out[(size_t)wid * OUT_F + fl * 8]     = o0;
    *(float4*)&out[(size_t)wid * OUT_F + fl * 8 + 4] = o1;
  }
}

extern "C" void kernel_launch(void* const* d_in, const int* in_sizes, int n_in,
                              void* d_out, int out_size, void* d_ws, size_t ws_size,
                              hipStream_t stream) {
  const float* x   = (const float*)d_in[0];
  const int* ei    = (const int*)d_in[1];
  const float* W1  = (const float*)d_in[2];
  const float* as1 = (const float*)d_in[3];
  const float* ad1 = (const float*)d_in[4];
  const float* b1  = (const float*)d_in[5];
  const float* W2  = (const float*)d_in[6];
  const float* as2 = (const float*)d_in[7];
  const float* ad2 = (const float*)d_in[8];
  const float* b2  = (const float*)d_in[9];
  float* out = (float*)d_out;

  float* ws = (float*)d_ws;
  float* a_s1   = ws;  ws += (size_t)N_NODES * HEADS1;
  float* a_d1   = ws;  ws += (size_t)N_NODES * HEADS1;
  float* a_s2   = ws;  ws += (size_t)N_NODES;
  float* a_d2   = ws;  ws += (size_t)N_NODES;
  unsigned short* h1bf   = (unsigned short*)ws;  ws += (size_t)N_NODES * HID / 2;
  unsigned short* out1bf = (unsigned short*)ws;  ws += (size_t)N_NODES * HID / 2;
  unsigned short* h2bf   = (unsigned short*)ws;  ws += (size_t)N_NODES * OUT_F / 2;
  unsigned short* W1t = (unsigned short*)ws;  ws += (IN_F * HID) / 2;
  unsigned short* W2t = (unsigned short*)ws;  ws += (HID * OUT_F) / 2;
  int* deg      = (int*)ws;  ws += (N_NODES + 1);
  int* rowptr   = (int*)ws;  ws += (N_NODES + 1);
  int* cursor   = (int*)ws;  ws += N_NODES;
  int* csr_src  = (int*)ws;  ws += ET;
  int* exq      = (int*)ws;  ws += N_NODES;
  int* bsum     = (int*)ws;  ws += NBLK;
  int* boff     = (int*)ws;  ws += NBLK;

  // ---- weight transpose+cast (tiny; independent) ----
  wt_kernel<<<dim3((IN_F * HID + 255) / 256), dim3(256), 0, stream>>>(W1, W1t, IN_F, HID);
  wt_kernel<<<dim3((HID * OUT_F + 255) / 256), dim3(256), 0, stream>>>(W2, W2t, HID, OUT_F);

  // ---- CSR build (dst-range partitioned) ----
  hipMemsetAsync(deg, 0, sizeof(int) * (N_NODES + 1), stream);
  deg_part_kernel<<<dim3(NRANGE * BPG), dim3(256), 0, stream>>>(ei, deg);
  scan1_kernel<<<dim3(NBLK), dim3(256), 0, stream>>>(deg, exq, bsum);
  scan2_kernel<<<dim3(1), dim3(256), 0, stream>>>(bsum, boff);
  scan3_kernel<<<dim3(NBLK), dim3(256), 0, stream>>>(exq, boff, rowptr, cursor);
  scatter_part_kernel<<<dim3(NRANGE * BPG), dim3(256), 0, stream>>>(ei, cursor, csr_src);

  // ---- layer 1 ----
  gemm1_mfma_kernel<<<dim3((N_NODES + 63) / 64), dim3(256), 0, stream>>>(x, W1t, as1, ad1, h1bf, a_s1, a_d1);
  agg1_csr_kernel<<<dim3((N_NODES + 3) / 4), dim3(256), 0, stream>>>(rowptr, csr_src, a_s1, a_d1, h1bf, b1, out1bf);

  // ---- layer 2 ----
  gemm2_mfma_kernel<<<dim3((N_NODES + 63) / 64), dim3(256), 0, stream>>>(out1bf, W2t, as2, ad2, h2bf, a_s2, a_d2);
  agg2_csr_kernel<<<dim3((N_NODES + 3) / 4), dim3(256), 0, stream>>>(rowptr, csr_src, a_s2, a_d2, h2bf, b2, out);
}

// Round 13
// 292.827 us; speedup vs baseline: 1.1822x; 1.0236x over previous
//
#include <hip/hip_runtime.h>
#include <math.h>

#define N_NODES 50000
#define E_EDGES 800000
#define ET (E_EDGES + N_NODES)   // edges + self loops
#define IN_F 256
#define HID 128
#define HEADS1 8
#define C1 16
#define OUT_F 64
#define NEG_SLOPE 0.2f
#define NBLK ((N_NODES + 255) / 256)   // 196 scan blocks
#define NRANGE 8
#define RSPAN ((N_NODES + NRANGE - 1) / NRANGE)   // 6250
#define BPG 256                                    // blocks per range-group

typedef __attribute__((ext_vector_type(8))) short short8;
typedef __attribute__((ext_vector_type(4))) float float4v;

__device__ __forceinline__ float lrelu(float v) { return v > 0.f ? v : NEG_SLOPE * v; }

__device__ __forceinline__ unsigned short f2bf(float f) {
  union { float f; unsigned u; } v; v.f = f;
  unsigned r = v.u + 0x7FFF + ((v.u >> 16) & 1);   // RNE
  return (unsigned short)(r >> 16);
}
__device__ __forceinline__ float bf2f(unsigned short u) {
  union { unsigned u; float f; } v; v.u = ((unsigned)u) << 16; return v.f;
}

// async global->LDS, 16B per lane; global addr is PER-LANE, lds dest = uniform base + lane*16
__device__ __forceinline__ void stage16(const void* g, void* l) {
  __builtin_amdgcn_global_load_lds((const __attribute__((address_space(1))) void*)g,
                                   (__attribute__((address_space(3))) void*)l, 16, 0, 0);
}
#define WAIT_VM0()   asm volatile("s_waitcnt vmcnt(0)" ::: "memory")
#define WAIT_LGKM0() asm volatile("s_waitcnt lgkmcnt(0)" ::: "memory")

// ---- W transpose+cast: Wt[n][k] bf16 from W[k][n] fp32 ----
__global__ __launch_bounds__(256) void wt_kernel(const float* __restrict__ W,
                                                 unsigned short* __restrict__ Wt,
                                                 int K, int Nc) {
  int i = blockIdx.x * 256 + threadIdx.x;
  if (i >= K * Nc) return;
  int n = i / K, k = i - n * K;
  Wt[i] = f2bf(W[k * Nc + n]);
}

// ---------------- GEMM1 (MFMA) + fused att1 ----------------
// Col-half per block (64 cols). B staged ONCE to LDS (32 KB, XOR-swizzled 16B
// chunks -> 2-way-max bank aliasing). A staged via global_load_lds into a
// per-wave 4-slice ring (depth-3 prefetch, manual vmcnt - the K-loop has NO
// register-consuming global loads, so the compiler inserts no vmcnt of its own).
__global__ __launch_bounds__(256) void gemm1_mfma_kernel(const float* __restrict__ x,
                                                         const unsigned short* __restrict__ W1t,
                                                         const float* __restrict__ att_src,
                                                         const float* __restrict__ att_dst,
                                                         unsigned short* __restrict__ h1bf,
                                                         float* __restrict__ a_s,
                                                         float* __restrict__ a_d) {
  __shared__ unsigned short Bls[64 * 256];   // 32 KB: [col][k], chunk j stored at j^(col&31)
  __shared__ float As[4][4][512];            // 32 KB: per-wave 4-slice A ring (16 rows x 32 f)
  const int ch = blockIdx.x & 1;
  const int rb = blockIdx.x >> 1;
  const int wv = threadIdx.x >> 6;
  const int lane = threadIdx.x & 63;
  const int wave = rb * 4 + wv;
  const int m0 = wave * 16;
  const int lm = lane & 15;
  const int quad = lane >> 4;
  const int c0 = ch * 64;

  // ---- stage this half's B (64 cols x 256 k) into LDS, swizzled ----
  {
    const int lrow = lane >> 5;              // which of 2 cols per instr
    const int jp = lane & 31;                // stored 16B-chunk position
#pragma unroll
    for (int s8 = 0; s8 < 8; ++s8) {
      int s = wv * 8 + s8;                   // staging instr 0..31
      int cl = 2 * s + lrow;                 // local col 0..63
      int j = jp ^ (cl & 31);                // global chunk fetched into slot jp
      stage16(W1t + ((size_t)(c0 + cl) * IN_F + j * 8),
              (unsigned short*)Bls + (size_t)s * 512);
    }
  }
  WAIT_VM0();
  __syncthreads();                           // only barrier in the kernel
  if (m0 >= N_NODES) return;                 // idle waves exit AFTER barrier

  // A staging lane map: rows r=lane>>3 (+8 for second instr), slot t'=lane&7
  // holds global chunk t' ^ (r&7)  (XOR swizzle kills the 16-way read conflict)
  const int ar0 = lane >> 3;                 // 0..7
  const int at0 = (lane & 7) ^ (ar0 & 7);
  const float* ga0 = x + (size_t)(m0 + ar0) * IN_F + at0 * 4;       // rows 0..7
  const float* ga1 = x + (size_t)(m0 + 8 + ar0) * IN_F + at0 * 4;   // rows 8..15 (same key)

  // prologue: prefetch chunks 0,1,2 (depth 3)
#pragma unroll
  for (int t = 0; t < 3; ++t) {
    stage16(ga0 + t * 32, &As[wv][t][0]);
    stage16(ga1 + t * 32, &As[wv][t][256]);
  }

  float4v acc[4];
#pragma unroll
  for (int nt = 0; nt < 4; ++nt) acc[nt] = (float4v){0.f, 0.f, 0.f, 0.f};

#pragma unroll
  for (int kk = 0; kk < 8; ++kk) {
    if (kk < 5) {
      stage16(ga0 + (kk + 3) * 32, &As[wv][(kk + 3) & 3][0]);
      stage16(ga1 + (kk + 3) * 32, &As[wv][(kk + 3) & 3][256]);
      asm volatile("s_waitcnt vmcnt(6)" ::: "memory");   // chunk kk landed; 3 in flight
    } else if (kk == 5) {
      asm volatile("s_waitcnt vmcnt(4)" ::: "memory");
    } else if (kk == 6) {
      asm volatile("s_waitcnt vmcnt(2)" ::: "memory");
    } else {
      asm volatile("s_waitcnt vmcnt(0)" ::: "memory");
    }
    const float4* rowp = (const float4*)&As[wv][kk & 3][lm * 32];
    int p0 = (2 * quad) ^ (lm & 7);
    float4 a0 = rowp[p0];                    // global floats quad*8 .. +3
    float4 a1 = rowp[p0 ^ 1];                // global floats quad*8+4 .. +7
    short8 a;
    a[0] = f2bf(a0.x); a[1] = f2bf(a0.y); a[2] = f2bf(a0.z); a[3] = f2bf(a0.w);
    a[4] = f2bf(a1.x); a[5] = f2bf(a1.y); a[6] = f2bf(a1.z); a[7] = f2bf(a1.w);
#pragma unroll
    for (int nt = 0; nt < 4; ++nt) {
      int c = nt * 16 + lm;                  // local col
      short8 b = *(const short8*)&Bls[(size_t)c * IN_F + (size_t)((kk * 4 + quad) ^ (c & 31)) * 8];
      acc[nt] = __builtin_amdgcn_mfma_f32_16x16x32_bf16(a, b, acc[nt], 0, 0, 0);
    }
  }

#pragma unroll
  for (int nt = 0; nt < 4; ++nt) {
#pragma unroll
    for (int r = 0; r < 4; ++r) {
      int row = m0 + quad * 4 + r;
      h1bf[(size_t)row * HID + c0 + nt * 16 + lm] = f2bf(acc[nt][r]);
    }
  }

  // ---- fused att1: this wave owns heads ch*4+nt ----
  float asv[4], adv[4];
#pragma unroll
  for (int nt = 0; nt < 4; ++nt) {
    asv[nt] = att_src[c0 + nt * 16 + lm];
    adv[nt] = att_dst[c0 + nt * 16 + lm];
  }
#pragma unroll
  for (int r = 0; r < 4; ++r) {
    int row = m0 + quad * 4 + r;
    float s[4], d[4];
#pragma unroll
    for (int nt = 0; nt < 4; ++nt) { s[nt] = acc[nt][r] * asv[nt]; d[nt] = acc[nt][r] * adv[nt]; }
#pragma unroll
    for (int m = 1; m < 16; m <<= 1) {
#pragma unroll
      for (int nt = 0; nt < 4; ++nt) { s[nt] += __shfl_xor(s[nt], m); d[nt] += __shfl_xor(d[nt], m); }
    }
    if (lm == 0) {
#pragma unroll
      for (int nt = 0; nt < 4; ++nt) {
        a_s[(size_t)row * HEADS1 + ch * 4 + nt] = s[nt];
        a_d[(size_t)row * HEADS1 + ch * 4 + nt] = d[nt];
      }
    }
  }
}

// ---------------- GEMM2 (MFMA) + fused att2; A staged via global_load_lds -------
__global__ __launch_bounds__(256) void gemm2_mfma_kernel(const unsigned short* __restrict__ in,
                                                         const unsigned short* __restrict__ W2t,
                                                         const float* __restrict__ att_src,
                                                         const float* __restrict__ att_dst,
                                                         unsigned short* __restrict__ h2bf,
                                                         float* __restrict__ a_s,
                                                         float* __restrict__ a_d) {
  __shared__ unsigned short Bs[4 * 512];          // 4 waves x (16 rows x 32 bf16) = 4KB
  const int wv = threadIdx.x >> 6;
  const int wave = blockIdx.x * 4 + wv;
  const int lane = threadIdx.x & 63;
  const int m0 = wave * 16;
  if (m0 >= N_NODES) return;
  const int lm = lane & 15;
  const int quad = lane >> 4;
  unsigned short* myA = &Bs[wv * 512];

  const unsigned short* gsrc = in + (size_t)(m0 + (lane >> 2)) * HID + (lane & 3) * 8;

  float4v acc[4];
#pragma unroll
  for (int nt = 0; nt < 4; ++nt) acc[nt] = (float4v){0.f, 0.f, 0.f, 0.f};

#pragma unroll
  for (int kk = 0; kk < 4; ++kk) {                // K = 4 x 32
    WAIT_LGKM0();
    stage16(gsrc + kk * 32, myA);
    short8 bfr[4];
#pragma unroll
    for (int nt = 0; nt < 4; ++nt)
      bfr[nt] = *(const short8*)&W2t[(size_t)(nt * 16 + lm) * HID + kk * 32 + quad * 8];
    WAIT_VM0();
    short8 a = *(const short8*)&myA[lm * 32 + quad * 8];
#pragma unroll
    for (int nt = 0; nt < 4; ++nt)
      acc[nt] = __builtin_amdgcn_mfma_f32_16x16x32_bf16(a, bfr[nt], acc[nt], 0, 0, 0);
  }

#pragma unroll
  for (int nt = 0; nt < 4; ++nt) {
#pragma unroll
    for (int r = 0; r < 4; ++r) {
      int row = m0 + quad * 4 + r;
      h2bf[(size_t)row * OUT_F + nt * 16 + lm] = f2bf(acc[nt][r]);
    }
  }

  // ---- fused att2: single head over 64 cols ----
  float as0 = att_src[lm], as1v = att_src[16 + lm], as2v = att_src[32 + lm], as3 = att_src[48 + lm];
  float ad0 = att_dst[lm], ad1v = att_dst[16 + lm], ad2v = att_dst[32 + lm], ad3 = att_dst[48 + lm];
#pragma unroll
  for (int r = 0; r < 4; ++r) {
    int row = m0 + quad * 4 + r;
    float s = acc[0][r] * as0 + acc[1][r] * as1v + acc[2][r] * as2v + acc[3][r] * as3;
    float d = acc[0][r] * ad0 + acc[1][r] * ad1v + acc[2][r] * ad2v + acc[3][r] * ad3;
#pragma unroll
    for (int m = 1; m < 16; m <<= 1) { s += __shfl_xor(s, m); d += __shfl_xor(d, m); }
    if (lm == 0) { a_s[row] = s; a_d[row] = d; }
  }
}

// ---------------- CSR construction (dst-range partitioned for L2 locality) ------
__global__ __launch_bounds__(256) void deg_part_kernel(const int* __restrict__ ei,
                                                       int* __restrict__ deg) {
  const int g = blockIdx.x & (NRANGE - 1);
  const int tg = (blockIdx.x >> 3) * 256 + threadIdx.x;   // thread idx in group
  const int lo = g * RSPAN, hi = lo + RSPAN;
  for (int e = tg; e < ET; e += BPG * 256) {
    int d = (e < E_EDGES) ? ei[E_EDGES + e] : (e - E_EDGES);
    if (d >= lo && d < hi) atomicAdd(&deg[d], 1);
  }
}

__global__ __launch_bounds__(256) void scatter_part_kernel(const int* __restrict__ ei,
                                                           int* __restrict__ cursor,
                                                           int* __restrict__ csr_src) {
  const int g = blockIdx.x & (NRANGE - 1);
  const int tg = (blockIdx.x >> 3) * 256 + threadIdx.x;
  const int lo = g * RSPAN, hi = lo + RSPAN;
  for (int e = tg; e < ET; e += BPG * 256) {
    int d = (e < E_EDGES) ? ei[E_EDGES + e] : (e - E_EDGES);
    if (d >= lo && d < hi) {
      int s = (e < E_EDGES) ? ei[e] : d;
      int pos = atomicAdd(&cursor[d], 1);
      csr_src[pos] = s;
    }
  }
}

__global__ __launch_bounds__(256) void scan1_kernel(const int* __restrict__ deg,
                                                    int* __restrict__ exq,
                                                    int* __restrict__ bsum) {
  __shared__ int sh[256];
  const int t = threadIdx.x;
  const int idx = blockIdx.x * 256 + t;
  int v = (idx < N_NODES) ? deg[idx] : 0;
  sh[t] = v;
  __syncthreads();
  for (int off = 1; off < 256; off <<= 1) {
    int u = (t >= off) ? sh[t - off] : 0;
    __syncthreads();
    sh[t] += u;
    __syncthreads();
  }
  if (idx < N_NODES) exq[idx] = sh[t] - v;
  if (t == 255) bsum[blockIdx.x] = sh[t];
}

__global__ __launch_bounds__(256) void scan2_kernel(const int* __restrict__ bsum,
                                                    int* __restrict__ boff) {
  __shared__ int sh[256];
  const int t = threadIdx.x;
  int v = (t < NBLK) ? bsum[t] : 0;
  sh[t] = v;
  __syncthreads();
  for (int off = 1; off < 256; off <<= 1) {
    int u = (t >= off) ? sh[t - off] : 0;
    __syncthreads();
    sh[t] += u;
    __syncthreads();
  }
  if (t < NBLK) boff[t] = sh[t] - v;
}

__global__ __launch_bounds__(256) void scan3_kernel(const int* __restrict__ exq,
                                                    const int* __restrict__ boff,
                                                    int* __restrict__ rowptr,
                                                    int* __restrict__ cursor) {
  const int idx = blockIdx.x * 256 + threadIdx.x;
  if (idx < N_NODES) {
    int r = exq[idx] + boff[blockIdx.x];
    rowptr[idx] = r;
    cursor[idx] = r;
  }
  if (idx == 0) rowptr[N_NODES] = ET;
}

// ---------------- agg1: wave/dst; 16-lane×16B row gathers (4 edges/instr) -------
__global__ __launch_bounds__(256) void agg1_csr_kernel(const int* __restrict__ rowptr,
                                                       const int* __restrict__ csr_src,
                                                       const float* __restrict__ a_s,
                                                       const float* __restrict__ a_d,
                                                       const unsigned short* __restrict__ h1bf,
                                                       const float* __restrict__ b1,
                                                       unsigned short* __restrict__ out1bf) {
  int wid = (blockIdx.x * 256 + threadIdx.x) >> 6;
  int lane = threadIdx.x & 63;
  if (wid >= N_NODES) return;
  const int fl = lane & 15;
  const int g  = lane >> 4;
  const int myh = fl >> 1;
  const float adn = a_d[(size_t)wid * HEADS1 + myh];
  const int start = rowptr[wid], end = rowptr[wid + 1];
  float acc[8];
#pragma unroll
  for (int k = 0; k < 8; ++k) acc[k] = 0.f;
  float wsum = 0.f;

  for (int i = start; i < end; i += 8) {
    int e0 = i + g, e1 = i + 4 + g;
    bool v0 = e0 < end, v1 = e1 < end;
    int s0 = csr_src[v0 ? e0 : start];
    int s1 = csr_src[v1 ? e1 : start];
    float l0 = a_s[(size_t)s0 * HEADS1 + myh];
    float l1 = a_s[(size_t)s1 * HEADS1 + myh];
    short8 r0 = *(const short8*)&h1bf[(size_t)s0 * HID + fl * 8];
    short8 r1 = *(const short8*)&h1bf[(size_t)s1 * HID + fl * 8];
    float w0 = v0 ? __expf(lrelu(l0 + adn)) : 0.f;
    float w1 = v1 ? __expf(lrelu(l1 + adn)) : 0.f;
#pragma unroll
    for (int k = 0; k < 8; ++k)
      acc[k] += w0 * bf2f((unsigned short)r0[k]) + w1 * bf2f((unsigned short)r1[k]);
    wsum += w0 + w1;
  }

#pragma unroll
  for (int k = 0; k < 8; ++k) {
    acc[k] += __shfl_xor(acc[k], 16);
    acc[k] += __shfl_xor(acc[k], 32);
  }
  wsum += __shfl_xor(wsum, 16);
  wsum += __shfl_xor(wsum, 32);

  if (g == 0) {
    float inv = 1.f / (wsum + 1e-16f);
    float4 blo = *(const float4*)&b1[fl * 8];
    float4 bhi = *(const float4*)&b1[fl * 8 + 4];
    float vv[8];
    vv[0] = acc[0] * inv + blo.x; vv[1] = acc[1] * inv + blo.y;
    vv[2] = acc[2] * inv + blo.z; vv[3] = acc[3] * inv + blo.w;
    vv[4] = acc[4] * inv + bhi.x; vv[5] = acc[5] * inv + bhi.y;
    vv[6] = acc[6] * inv + bhi.z; vv[7] = acc[7] * inv + bhi.w;
    short8 o;
#pragma unroll
    for (int k = 0; k < 8; ++k) {
      float e = vv[k] > 0.f ? vv[k] : expm1f(vv[k]);
      o[k] = (short)f2bf(e);
    }
    *(short8*)&out1bf[(size_t)wid * HID + fl * 8] = o;
  }
}

// ---------------- agg2: wave/dst; 8-lane×16B row gathers (8 edges/instr) --------
__global__ __launch_bounds__(256) void agg2_csr_kernel(const int* __restrict__ rowptr,
                                                       const int* __restrict__ csr_src,
                                                       const float* __restrict__ a_s,
                                                       const float* __restrict__ a_d,
                                                       const unsigned short* __restrict__ h2bf,
                                                       const float* __restrict__ b2,
                                                       float* __restrict__ out) {
  int wid = (blockIdx.x * 256 + threadIdx.x) >> 6;
  int lane = threadIdx.x & 63;
  if (wid >= N_NODES) return;
  const int fl = lane & 7;       // owns feats [8*fl, 8*fl+8)
  const int g  = lane >> 3;      // edge group 0..7
  const float adn = a_d[wid];
  const int start = rowptr[wid], end = rowptr[wid + 1];
  float acc[8];
#pragma unroll
  for (int k = 0; k < 8; ++k) acc[k] = 0.f;
  float wsum = 0.f;

  for (int i = start; i < end; i += 16) {
    int e0 = i + g, e1 = i + 8 + g;
    bool v0 = e0 < end, v1 = e1 < end;
    int s0 = csr_src[v0 ? e0 : start];
    int s1 = csr_src[v1 ? e1 : start];
    float l0 = a_s[s0];
    float l1 = a_s[s1];
    short8 r0 = *(const short8*)&h2bf[(size_t)s0 * OUT_F + fl * 8];
    short8 r1 = *(const short8*)&h2bf[(size_t)s1 * OUT_F + fl * 8];
    float w0 = v0 ? __expf(lrelu(l0 + adn)) : 0.f;
    float w1 = v1 ? __expf(lrelu(l1 + adn)) : 0.f;
#pragma unroll
    for (int k = 0; k < 8; ++k)
      acc[k] += w0 * bf2f((unsigned short)r0[k]) + w1 * bf2f((unsigned short)r1[k]);
    wsum += w0 + w1;
  }

#pragma unroll
  for (int k = 0; k < 8; ++k) {
    acc[k] += __shfl_xor(acc[k], 8);
    acc[k] += __shfl_xor(acc[k], 16);
    acc[k] += __shfl_xor(acc[k], 32);
  }
  wsum += __shfl_xor(wsum, 8);
  wsum += __shfl_xor(wsum, 16);
  wsum += __shfl_xor(wsum, 32);

  float inv = 1.f / (wsum + 1e-16f);
  float4 blo = *(const float4*)&b2[fl * 8];
  float4 bhi = *(const float4*)&b2[fl * 8 + 4];
  float vv[8];
  vv[0] = acc[0] * inv + blo.x; vv[1] = acc[1] * inv + blo.y;
  vv[2] = acc[2] * inv + blo.z; vv[3] = acc[3] * inv + blo.w;
  vv[4] = acc[4] * inv + bhi.x; vv[5] = acc[5] * inv + bhi.y;
  vv[6] = acc[6] * inv + bhi.z; vv[7] = acc[7] * inv + bhi.w;
  float m = vv[0];
#pragma unroll
  for (int k = 1; k < 8; ++k) m = fmaxf(m, vv[k]);
#pragma unroll
  for (int msk = 1; msk < 8; msk <<= 1) m = fmaxf(m, __shfl_xor(m, msk));
  float sm = 0.f;
#pragma unroll
  for (int k = 0; k < 8; ++k) sm += __expf(vv[k] - m);
#pragma unroll
  for (int msk = 1; msk < 8; msk <<= 1) sm += __shfl_xor(sm, msk);
  float lse = m + __logf(sm);
  if (g == 0) {
    float4 o0 = make_float4(vv[0] - lse, vv[1] - lse, vv[2] - lse, vv[3] - lse);
    float4 o1 = make_float4(vv[4] - lse, vv[5] - lse, vv[6] - lse, vv[7] - lse);
    *(float4*)&out[(size_t)wid * OUT_F + fl * 8]     = o0;
    *(float4*)&out[(size_t)wid * OUT_F + fl * 8 + 4] = o1;
  }
}

extern "C" void kernel_launch(void* const* d_in, const int* in_sizes, int n_in,
                              void* d_out, int out_size, void* d_ws, size_t ws_size,
                              hipStream_t stream) {
  const float* x   = (const float*)d_in[0];
  const int* ei    = (const int*)d_in[1];
  const float* W1  = (const float*)d_in[2];
  const float* as1 = (const float*)d_in[3];
  const float* ad1 = (const float*)d_in[4];
  const float* b1  = (const float*)d_in[5];
  const float* W2  = (const float*)d_in[6];
  const float* as2 = (const float*)d_in[7];
  const float* ad2 = (const float*)d_in[8];
  const float* b2  = (const float*)d_in[9];
  float* out = (float*)d_out;

  float* ws = (float*)d_ws;
  float* a_s1   = ws;  ws += (size_t)N_NODES * HEADS1;
  float* a_d1   = ws;  ws += (size_t)N_NODES * HEADS1;
  float* a_s2   = ws;  ws += (size_t)N_NODES;
  float* a_d2   = ws;  ws += (size_t)N_NODES;
  unsigned short* h1bf   = (unsigned short*)ws;  ws += (size_t)N_NODES * HID / 2;
  unsigned short* out1bf = (unsigned short*)ws;  ws += (size_t)N_NODES * HID / 2;
  unsigned short* h2bf   = (unsigned short*)ws;  ws += (size_t)N_NODES * OUT_F / 2;
  unsigned short* W1t = (unsigned short*)ws;  ws += (IN_F * HID) / 2;
  unsigned short* W2t = (unsigned short*)ws;  ws += (HID * OUT_F) / 2;
  int* deg      = (int*)ws;  ws += (N_NODES + 1);
  int* rowptr   = (int*)ws;  ws += (N_NODES + 1);
  int* cursor   = (int*)ws;  ws += N_NODES;
  int* csr_src  = (int*)ws;  ws += ET;
  int* exq      = (int*)ws;  ws += N_NODES;
  int* bsum     = (int*)ws;  ws += NBLK;
  int* boff     = (int*)ws;  ws += NBLK;

  // ---- weight transpose+cast (tiny; independent) ----
  wt_kernel<<<dim3((IN_F * HID + 255) / 256), dim3(256), 0, stream>>>(W1, W1t, IN_F, HID);
  wt_kernel<<<dim3((HID * OUT_F + 255) / 256), dim3(256), 0, stream>>>(W2, W2t, HID, OUT_F);

  // ---- CSR build (dst-range partitioned) ----
  hipMemsetAsync(deg, 0, sizeof(int) * (N_NODES + 1), stream);
  deg_part_kernel<<<dim3(NRANGE * BPG), dim3(256), 0, stream>>>(ei, deg);
  scan1_kernel<<<dim3(NBLK), dim3(256), 0, stream>>>(deg, exq, bsum);
  scan2_kernel<<<dim3(1), dim3(256), 0, stream>>>(bsum, boff);
  scan3_kernel<<<dim3(NBLK), dim3(256), 0, stream>>>(exq, boff, rowptr, cursor);
  scatter_part_kernel<<<dim3(NRANGE * BPG), dim3(256), 0, stream>>>(ei, cursor, csr_src);

  // ---- layer 1 ----
  gemm1_mfma_kernel<<<dim3(((N_NODES + 63) / 64) * 2), dim3(256), 0, stream>>>(x, W1t, as1, ad1, h1bf, a_s1, a_d1);
  agg1_csr_kernel<<<dim3((N_NODES + 3) / 4), dim3(256), 0, stream>>>(rowptr, csr_src, a_s1, a_d1, h1bf, b1, out1bf);

  // ---- layer 2 ----
  gemm2_mfma_kernel<<<dim3((N_NODES + 63) / 64), dim3(256), 0, stream>>>(out1bf, W2t, as2, ad2, h2bf, a_s2, a_d2);
  agg2_csr_kernel<<<dim3((N_NODES + 3) / 4), dim3(256), 0, stream>>>(rowptr, csr_src, a_s2, a_d2, h2bf, b2, out);
}